// Round 1
// baseline (509.621 us; speedup 1.0000x reference)
//
#include <hip/hip_runtime.h>

// MultiHeadAttention: out = softmax((XWq^T)(XWk^T)^T / 8) (XWv^T) Wo^T
// B=2, L=2048, DIM=1024, H=16, D=64. fp32 in/out, bf16 MFMA compute.

#define DIMN 1024
#define NH 16
#define HD 64
#define BB 2
#define LL 2048

typedef float f32x4 __attribute__((ext_vector_type(4)));
typedef short s16x8 __attribute__((ext_vector_type(8)));

static __device__ __forceinline__ unsigned short f2bf(float f) {
  unsigned u = __float_as_uint(f);
  u += 0x7fffu + ((u >> 16) & 1u);   // RNE
  return (unsigned short)(u >> 16);
}

static __device__ __forceinline__ s16x8 cvt8(float4 a, float4 b) {
  s16x8 r;
  r[0] = (short)f2bf(a.x); r[1] = (short)f2bf(a.y);
  r[2] = (short)f2bf(a.z); r[3] = (short)f2bf(a.w);
  r[4] = (short)f2bf(b.x); r[5] = (short)f2bf(b.y);
  r[6] = (short)f2bf(b.z); r[7] = (short)f2bf(b.w);
  return r;
}

// ---------------- fused QKV projection ----------------
// grid (4096/64, 3072/64), block 64 (1 wave). Wave computes 64x64 of C = X * W^T.
// Output: bf16 [B,H,L,D]; Q pre-scaled by 1/8 (exact in bf16).
__global__ __launch_bounds__(64) void qkv_proj(
    const float* __restrict__ X, const float* __restrict__ Wq,
    const float* __restrict__ Wk, const float* __restrict__ Wv,
    unsigned short* __restrict__ Qb, unsigned short* __restrict__ Kb,
    unsigned short* __restrict__ Vb) {
  const int m0 = blockIdx.x * 64;
  const int n0g = blockIdx.y * 64;
  const int sel = n0g >> 10;
  const int n0 = n0g & 1023;
  const float* W = (sel == 0) ? Wq : (sel == 1) ? Wk : Wv;
  unsigned short* Out = (sel == 0) ? Qb : (sel == 1) ? Kb : Vb;
  const float scale = (sel == 0) ? 0.125f : 1.0f;
  const int lane = threadIdx.x;
  const int c = lane & 15, quad = lane >> 4;

  f32x4 zero = {0.f, 0.f, 0.f, 0.f};
  f32x4 acc[4][4];
#pragma unroll
  for (int i = 0; i < 4; ++i)
#pragma unroll
    for (int j = 0; j < 4; ++j) acc[i][j] = zero;

  const float* ab = X + (m0 + c) * DIMN + quad * 8;
  const float* bb = W + (n0 + c) * DIMN + quad * 8;

  for (int k0 = 0; k0 < DIMN; k0 += 32) {
    s16x8 a[4], b[4];
#pragma unroll
    for (int i = 0; i < 4; ++i) {
      const float* p = ab + i * 16 * DIMN + k0;
      a[i] = cvt8(*(const float4*)p, *(const float4*)(p + 4));
    }
#pragma unroll
    for (int j = 0; j < 4; ++j) {
      const float* p = bb + j * 16 * DIMN + k0;
      b[j] = cvt8(*(const float4*)p, *(const float4*)(p + 4));
    }
#pragma unroll
    for (int i = 0; i < 4; ++i)
#pragma unroll
      for (int j = 0; j < 4; ++j)
        acc[i][j] = __builtin_amdgcn_mfma_f32_16x16x32_bf16(a[i], b[j], acc[i][j], 0, 0, 0);
  }

#pragma unroll
  for (int i = 0; i < 4; ++i) {
#pragma unroll
    for (int j = 0; j < 4; ++j) {
#pragma unroll
      for (int r = 0; r < 4; ++r) {
        int row = m0 + i * 16 + quad * 4 + r;  // 0..4095
        int nl = n0 + j * 16 + c;              // 0..1023
        int bi = row >> 11, li = row & 2047;
        int h = nl >> 6, d = nl & 63;
        Out[((bi * NH + h) * LL + li) * HD + d] = f2bf(acc[i][j][r] * scale);
      }
    }
  }
}

// ---------------- flash attention ----------------
// grid (L/64, B*NH), block 256 (4 waves). Wave owns 16 query rows.
__global__ __launch_bounds__(256) void attn(
    const unsigned short* __restrict__ Qb, const unsigned short* __restrict__ Kb,
    const unsigned short* __restrict__ Vb, unsigned short* __restrict__ AO) {
  __shared__ __align__(16) unsigned short Kl[32][72];      // keys x d, padded
  __shared__ __align__(16) unsigned short Vt[64][40];      // d x keys, padded
  __shared__ __align__(16) unsigned short Pl[4][16][40];   // per-wave P, padded

  const int bh = blockIdx.y;
  const int tid = threadIdx.x;
  const int w = tid >> 6, lane = tid & 63;
  const int c = lane & 15, quad = lane >> 4;
  const int q0 = blockIdx.x * 64 + w * 16;

  const unsigned short* Qh = Qb + bh * LL * HD;
  const unsigned short* Kh = Kb + bh * LL * HD;
  const unsigned short* Vh = Vb + bh * LL * HD;

  // preload Q A-frags for this wave's 16 rows (Q already scaled by 1/8)
  s16x8 qf[2];
#pragma unroll
  for (int f = 0; f < 2; ++f)
    qf[f] = *(const s16x8*)(Qh + (q0 + c) * HD + f * 32 + quad * 8);

  float mrow[4], lrow[4];
  f32x4 o[4];
  f32x4 zero = {0.f, 0.f, 0.f, 0.f};
#pragma unroll
  for (int r = 0; r < 4; ++r) { mrow[r] = -1e30f; lrow[r] = 0.f; }
#pragma unroll
  for (int dc = 0; dc < 4; ++dc) o[dc] = zero;

  const int srow = tid >> 3;        // 0..31 (key row in tile)
  const int sd0 = (tid & 7) << 3;   // 0..56 (d offset)

  for (int k0 = 0; k0 < LL; k0 += 32) {
    __syncthreads();
    {
      uint4 kvec = *(const uint4*)(Kh + (k0 + srow) * HD + sd0);
      *(uint4*)&Kl[srow][sd0] = kvec;
      uint4 vvec = *(const uint4*)(Vh + (k0 + srow) * HD + sd0);
      union { uint4 v; unsigned short s[8]; } u;
      u.v = vvec;
#pragma unroll
      for (int j = 0; j < 8; ++j) Vt[sd0 + j][srow] = u.s[j];
    }
    __syncthreads();

    // S = Q K^T for two 16-key tiles (C-layout: row=quad*4+r, col=c=key)
    f32x4 s0 = zero, s1 = zero;
    {
      s16x8 kf;
      kf = *(const s16x8*)&Kl[c][quad * 8];
      s0 = __builtin_amdgcn_mfma_f32_16x16x32_bf16(qf[0], kf, s0, 0, 0, 0);
      kf = *(const s16x8*)&Kl[c][32 + quad * 8];
      s0 = __builtin_amdgcn_mfma_f32_16x16x32_bf16(qf[1], kf, s0, 0, 0, 0);
      kf = *(const s16x8*)&Kl[16 + c][quad * 8];
      s1 = __builtin_amdgcn_mfma_f32_16x16x32_bf16(qf[0], kf, s1, 0, 0, 0);
      kf = *(const s16x8*)&Kl[16 + c][32 + quad * 8];
      s1 = __builtin_amdgcn_mfma_f32_16x16x32_bf16(qf[1], kf, s1, 0, 0, 0);
    }

    // online softmax, one row per accumulator register
#pragma unroll
    for (int r = 0; r < 4; ++r) {
      float v = fmaxf(s0[r], s1[r]);
      v = fmaxf(v, __shfl_xor(v, 1));
      v = fmaxf(v, __shfl_xor(v, 2));
      v = fmaxf(v, __shfl_xor(v, 4));
      v = fmaxf(v, __shfl_xor(v, 8));
      float mnew = fmaxf(mrow[r], v);
      float alpha = __expf(mrow[r] - mnew);
      mrow[r] = mnew;
      float p0 = __expf(s0[r] - mnew);
      float p1 = __expf(s1[r] - mnew);
      float rs = p0 + p1;
      rs += __shfl_xor(rs, 1);
      rs += __shfl_xor(rs, 2);
      rs += __shfl_xor(rs, 4);
      rs += __shfl_xor(rs, 8);
      lrow[r] = lrow[r] * alpha + rs;
#pragma unroll
      for (int dc = 0; dc < 4; ++dc) o[dc][r] *= alpha;
      Pl[w][quad * 4 + r][c] = f2bf(p0);
      Pl[w][quad * 4 + r][16 + c] = f2bf(p1);
    }

    // in-wave LDS round-trip: make P writes visible before A-frag read
    asm volatile("s_waitcnt lgkmcnt(0)" ::: "memory");

    // O += P V  (A = P[16x32], B = V[32 x 16d] from transposed LDS)
    s16x8 pf = *(const s16x8*)&Pl[w][c][quad * 8];
#pragma unroll
    for (int dc = 0; dc < 4; ++dc) {
      s16x8 vf = *(const s16x8*)&Vt[dc * 16 + c][quad * 8];
      o[dc] = __builtin_amdgcn_mfma_f32_16x16x32_bf16(pf, vf, o[dc], 0, 0, 0);
    }
  }

  // epilogue: AO is [B, L, DIM] bf16
  const int bi = bh >> 4, h = bh & 15;
#pragma unroll
  for (int r = 0; r < 4; ++r) {
    float inv = 1.0f / lrow[r];
    int li = q0 + quad * 4 + r;
#pragma unroll
    for (int dc = 0; dc < 4; ++dc)
      AO[(bi * LL + li) * DIMN + h * HD + dc * 16 + c] = f2bf(o[dc][r] * inv);
  }
}

// ---------------- output projection ----------------
// grid (4096/64, 1024/64), block 64. C = AO(bf16) * Wo^T -> fp32 d_out.
__global__ __launch_bounds__(64) void o_proj(
    const unsigned short* __restrict__ A, const float* __restrict__ Wo,
    float* __restrict__ Out) {
  const int m0 = blockIdx.x * 64, n0 = blockIdx.y * 64;
  const int lane = threadIdx.x;
  const int c = lane & 15, quad = lane >> 4;

  f32x4 zero = {0.f, 0.f, 0.f, 0.f};
  f32x4 acc[4][4];
#pragma unroll
  for (int i = 0; i < 4; ++i)
#pragma unroll
    for (int j = 0; j < 4; ++j) acc[i][j] = zero;

  const unsigned short* ab = A + (m0 + c) * DIMN + quad * 8;
  const float* bb = Wo + (n0 + c) * DIMN + quad * 8;

  for (int k0 = 0; k0 < DIMN; k0 += 32) {
    s16x8 a[4], b[4];
#pragma unroll
    for (int i = 0; i < 4; ++i)
      a[i] = *(const s16x8*)(ab + i * 16 * DIMN + k0);
#pragma unroll
    for (int j = 0; j < 4; ++j) {
      const float* p = bb + j * 16 * DIMN + k0;
      b[j] = cvt8(*(const float4*)p, *(const float4*)(p + 4));
    }
#pragma unroll
    for (int i = 0; i < 4; ++i)
#pragma unroll
      for (int j = 0; j < 4; ++j)
        acc[i][j] = __builtin_amdgcn_mfma_f32_16x16x32_bf16(a[i], b[j], acc[i][j], 0, 0, 0);
  }

#pragma unroll
  for (int i = 0; i < 4; ++i)
#pragma unroll
    for (int j = 0; j < 4; ++j)
#pragma unroll
      for (int r = 0; r < 4; ++r)
        Out[(m0 + i * 16 + quad * 4 + r) * DIMN + n0 + j * 16 + c] = acc[i][j][r];
}

extern "C" void kernel_launch(void* const* d_in, const int* in_sizes, int n_in,
                              void* d_out, int out_size, void* d_ws, size_t ws_size,
                              hipStream_t stream) {
  const float* X = (const float*)d_in[0];
  const float* Wq = (const float*)d_in[1];
  const float* Wk = (const float*)d_in[2];
  const float* Wv = (const float*)d_in[3];
  const float* Wo = (const float*)d_in[4];
  float* Out = (float*)d_out;

  const size_t nqkv = (size_t)BB * NH * LL * HD;  // 4,194,304 elements
  unsigned short* Qb = (unsigned short*)d_ws;
  unsigned short* Kb = Qb + nqkv;
  unsigned short* Vb = Kb + nqkv;
  unsigned short* AO = Vb + nqkv;   // total 32 MiB of ws

  qkv_proj<<<dim3(64, 48), 64, 0, stream>>>(X, Wq, Wk, Wv, Qb, Kb, Vb);
  attn<<<dim3(LL / 64, BB * NH), 256, 0, stream>>>(Qb, Kb, Vb, AO);
  o_proj<<<dim3(64, 16), 64, 0, stream>>>(AO, Wo, Out);
}

// Round 2
// 275.506 us; speedup vs baseline: 1.8498x; 1.8498x over previous
//
#include <hip/hip_runtime.h>

// MultiHeadAttention: out = softmax((XWq^T)(XWk^T)^T / 8) (XWv^T) Wo^T
// B=2, L=2048, DIM=1024, H=16, D=64. fp32 in/out, bf16 MFMA compute.
//
// R2: (1) no-max softmax: p=exp2(s*log2e), normalize at end (|s|<=~8 << 88,
//     exact softmax identity); (2) V^T produced by operand-swapped MFMA in the
//     projection (global [B,H,D,L]) -> no LDS transpose; (3) P stored as
//     v_perm-packed bf16 pairs in interleaved key order, V LDS tile staged in
//     the SAME key order (PV is key-order invariant) -> all LDS ops b32/b128;
//     (4) 64 keys/iter; (5) X/W pre-converted to bf16 once (ws>=48MiB path).

#define DIMN 1024
#define NH 16
#define HD 64
#define BB 2
#define LL 2048

typedef float f32x4 __attribute__((ext_vector_type(4)));
typedef short s16x8 __attribute__((ext_vector_type(8)));

#define QSCALE 0.18033688011112042f  // log2(e)/8, folds softmax exp2 domain

static __device__ __forceinline__ unsigned short f2bf(float f) {
  unsigned u = __float_as_uint(f);
  u += 0x7fffu + ((u >> 16) & 1u);   // RNE
  return (unsigned short)(u >> 16);
}
static __device__ __forceinline__ unsigned packbf2(float lo, float hi) {
  return (unsigned)f2bf(lo) | ((unsigned)f2bf(hi) << 16);
}
static __device__ __forceinline__ float xexp2(float x) {
#if __has_builtin(__builtin_amdgcn_exp2f)
  return __builtin_amdgcn_exp2f(x);
#else
  return exp2f(x);
#endif
}
static __device__ __forceinline__ s16x8 cvt8(float4 a, float4 b) {
  s16x8 r;
  r[0] = (short)f2bf(a.x); r[1] = (short)f2bf(a.y);
  r[2] = (short)f2bf(a.z); r[3] = (short)f2bf(a.w);
  r[4] = (short)f2bf(b.x); r[5] = (short)f2bf(b.y);
  r[6] = (short)f2bf(b.z); r[7] = (short)f2bf(b.w);
  return r;
}

// ---------------- fp32 -> bf16 pre-convert (X + 4 weights) ----------------
// grid (2048, 5) x 256. seg0: X (4M elems). seg1..4: Wq/Wk/Wv/Wo (1M each).
// out layout: Xb[0,4M) Wq[4M,5M) Wk[5M,6M) Wv[6M,7M) Wo[7M,8M)
__global__ __launch_bounds__(256) void cvt_all(
    const float* __restrict__ X, const float* __restrict__ Wq,
    const float* __restrict__ Wk, const float* __restrict__ Wv,
    const float* __restrict__ Wo, unsigned short* __restrict__ out) {
  const int seg = blockIdx.y;
  const float* src;
  unsigned short* dst;
  size_t n;
  if (seg == 0) { src = X; dst = out; n = (size_t)1 << 22; }
  else {
    src = (seg == 1) ? Wq : (seg == 2) ? Wk : (seg == 3) ? Wv : Wo;
    dst = out + ((size_t)1 << 22) + (size_t)(seg - 1) * (1u << 20);
    n = (size_t)1 << 20;
  }
  size_t i = ((size_t)blockIdx.x * 256 + threadIdx.x) * 8;
  if (i >= n) return;
  float4 v0 = *(const float4*)(src + i);
  float4 v1 = *(const float4*)(src + i + 4);
  uint4 o;
  o.x = packbf2(v0.x, v0.y); o.y = packbf2(v0.z, v0.w);
  o.z = packbf2(v1.x, v1.y); o.w = packbf2(v1.z, v1.w);
  *(uint4*)(dst + i) = o;
}

// ---------------- fused QKV projection (bf16 inputs) ----------------
// grid (64, 48), block 64 (1 wave): 64x64 tile of C = X * W^T.
// sel 0: Q [B,H,L,D] scaled by log2e/8; sel 1: K [B,H,L,D];
// sel 2: operand-swapped MFMA -> V^T directly, stored [B,H,D,L].
__global__ __launch_bounds__(64) void qkv_proj_b(
    const unsigned short* __restrict__ Xb, const unsigned short* __restrict__ Wb,
    unsigned short* __restrict__ Qb, unsigned short* __restrict__ Kb,
    unsigned short* __restrict__ VT) {
  const int m0 = blockIdx.x * 64;
  const int n0g = blockIdx.y * 64;
  const int sel = n0g >> 10;
  const int n0 = n0g & 1023;
  const unsigned short* W = Wb + (size_t)sel * (1u << 20);
  const int lane = threadIdx.x;
  const int c = lane & 15, quad = lane >> 4;

  f32x4 zero = {0.f, 0.f, 0.f, 0.f};
  f32x4 acc[4][4];
#pragma unroll
  for (int i = 0; i < 4; ++i)
#pragma unroll
    for (int j = 0; j < 4; ++j) acc[i][j] = zero;

  const unsigned short* ab = Xb + (size_t)(m0 + c) * DIMN + quad * 8;
  const unsigned short* bb = W + (size_t)(n0 + c) * DIMN + quad * 8;

  if (sel != 2) {
    for (int k0 = 0; k0 < DIMN; k0 += 32) {
      s16x8 a[4], b[4];
#pragma unroll
      for (int i = 0; i < 4; ++i) a[i] = *(const s16x8*)(ab + i * 16 * DIMN + k0);
#pragma unroll
      for (int j = 0; j < 4; ++j) b[j] = *(const s16x8*)(bb + j * 16 * DIMN + k0);
#pragma unroll
      for (int i = 0; i < 4; ++i)
#pragma unroll
        for (int j = 0; j < 4; ++j)
          acc[i][j] = __builtin_amdgcn_mfma_f32_16x16x32_bf16(a[i], b[j], acc[i][j], 0, 0, 0);
    }
    unsigned short* Out = (sel == 0) ? Qb : Kb;
    const float scale = (sel == 0) ? QSCALE : 1.0f;
#pragma unroll
    for (int i = 0; i < 4; ++i)
#pragma unroll
      for (int j = 0; j < 4; ++j)
#pragma unroll
        for (int r = 0; r < 4; ++r) {
          int row = m0 + i * 16 + quad * 4 + r;
          int nl = n0 + j * 16 + c;
          int bi = row >> 11, li = row & 2047;
          int h = nl >> 6, d = nl & 63;
          Out[(((size_t)bi * NH + h) * LL + li) * HD + d] = f2bf(acc[i][j][r] * scale);
        }
  } else {
    for (int k0 = 0; k0 < DIMN; k0 += 32) {
      s16x8 a[4], b[4];
#pragma unroll
      for (int i = 0; i < 4; ++i) a[i] = *(const s16x8*)(ab + i * 16 * DIMN + k0);
#pragma unroll
      for (int j = 0; j < 4; ++j) b[j] = *(const s16x8*)(bb + j * 16 * DIMN + k0);
#pragma unroll
      for (int i = 0; i < 4; ++i)
#pragma unroll
        for (int j = 0; j < 4; ++j)  // swapped -> C^T in regs
          acc[i][j] = __builtin_amdgcn_mfma_f32_16x16x32_bf16(b[j], a[i], acc[i][j], 0, 0, 0);
    }
#pragma unroll
    for (int i = 0; i < 4; ++i)
#pragma unroll
      for (int j = 0; j < 4; ++j)
#pragma unroll
        for (int r = 0; r < 4; ++r) {
          int n = n0 + j * 16 + quad * 4 + r;  // d/h index
          int l = m0 + i * 16 + c;             // sequence index
          int h = n >> 6, d = n & 63;
          int bi = l >> 11, li = l & 2047;
          VT[(((size_t)bi * NH + h) * HD + d) * LL + li] = f2bf(acc[i][j][r]);
        }
  }
}

// ---------------- fused QKV projection (fp32 fallback) ----------------
__global__ __launch_bounds__(64) void qkv_proj_f(
    const float* __restrict__ X, const float* __restrict__ Wq,
    const float* __restrict__ Wk, const float* __restrict__ Wv,
    unsigned short* __restrict__ Qb, unsigned short* __restrict__ Kb,
    unsigned short* __restrict__ VT) {
  const int m0 = blockIdx.x * 64;
  const int n0g = blockIdx.y * 64;
  const int sel = n0g >> 10;
  const int n0 = n0g & 1023;
  const float* W = (sel == 0) ? Wq : (sel == 1) ? Wk : Wv;
  const int lane = threadIdx.x;
  const int c = lane & 15, quad = lane >> 4;

  f32x4 zero = {0.f, 0.f, 0.f, 0.f};
  f32x4 acc[4][4];
#pragma unroll
  for (int i = 0; i < 4; ++i)
#pragma unroll
    for (int j = 0; j < 4; ++j) acc[i][j] = zero;

  const float* ab = X + (size_t)(m0 + c) * DIMN + quad * 8;
  const float* bb = W + (size_t)(n0 + c) * DIMN + quad * 8;

  for (int k0 = 0; k0 < DIMN; k0 += 32) {
    s16x8 a[4], b[4];
#pragma unroll
    for (int i = 0; i < 4; ++i) {
      const float* p = ab + i * 16 * DIMN + k0;
      a[i] = cvt8(*(const float4*)p, *(const float4*)(p + 4));
    }
#pragma unroll
    for (int j = 0; j < 4; ++j) {
      const float* p = bb + j * 16 * DIMN + k0;
      b[j] = cvt8(*(const float4*)p, *(const float4*)(p + 4));
    }
    if (sel != 2) {
#pragma unroll
      for (int i = 0; i < 4; ++i)
#pragma unroll
        for (int j = 0; j < 4; ++j)
          acc[i][j] = __builtin_amdgcn_mfma_f32_16x16x32_bf16(a[i], b[j], acc[i][j], 0, 0, 0);
    } else {
#pragma unroll
      for (int i = 0; i < 4; ++i)
#pragma unroll
        for (int j = 0; j < 4; ++j)
          acc[i][j] = __builtin_amdgcn_mfma_f32_16x16x32_bf16(b[j], a[i], acc[i][j], 0, 0, 0);
    }
  }

  if (sel != 2) {
    unsigned short* Out = (sel == 0) ? Qb : Kb;
    const float scale = (sel == 0) ? QSCALE : 1.0f;
#pragma unroll
    for (int i = 0; i < 4; ++i)
#pragma unroll
      for (int j = 0; j < 4; ++j)
#pragma unroll
        for (int r = 0; r < 4; ++r) {
          int row = m0 + i * 16 + quad * 4 + r;
          int nl = n0 + j * 16 + c;
          int bi = row >> 11, li = row & 2047;
          int h = nl >> 6, d = nl & 63;
          Out[(((size_t)bi * NH + h) * LL + li) * HD + d] = f2bf(acc[i][j][r] * scale);
        }
  } else {
#pragma unroll
    for (int i = 0; i < 4; ++i)
#pragma unroll
      for (int j = 0; j < 4; ++j)
#pragma unroll
        for (int r = 0; r < 4; ++r) {
          int n = n0 + j * 16 + quad * 4 + r;
          int l = m0 + i * 16 + c;
          int h = n >> 6, d = n & 63;
          int bi = l >> 11, li = l & 2047;
          VT[(((size_t)bi * NH + h) * HD + d) * LL + li] = f2bf(acc[i][j][r]);
        }
  }
}

// ---------------- flash attention, no-max softmax ----------------
// grid (32, B*NH), block 256 (4 waves); wave owns 16 q rows, 64 keys/iter.
// Q is pre-scaled by log2e/8 so p = exp2(s) is exactly softmax-unnormalized.
// Key storage order within a 64-tile is interleaved: short index p = h*32+2c+t
// holds key h*32 + c + 16t; P and V LDS tiles both use it (sum over keys is
// order-invariant), making every LDS access b32/b128.
__global__ __launch_bounds__(256) void attn2(
    const unsigned short* __restrict__ Qb, const unsigned short* __restrict__ Kb,
    const unsigned short* __restrict__ VT, unsigned short* __restrict__ AO) {
  __shared__ __align__(16) unsigned short Kl[64][72];     // key x d
  __shared__ __align__(16) unsigned short Vtl[64][72];    // d x p(interleaved key)
  __shared__ __align__(16) unsigned short Pl[4][16][72];  // per wave: qrow x p

  const int bh = blockIdx.y;
  const int tid = threadIdx.x;
  const int w = tid >> 6, lane = tid & 63;
  const int c = lane & 15, quad = lane >> 4;
  const int q0 = blockIdx.x * 64 + w * 16;

  const unsigned short* Qh = Qb + (size_t)bh * LL * HD;
  const unsigned short* Kh = Kb + (size_t)bh * LL * HD;
  const unsigned short* Vh = VT + (size_t)bh * HD * LL;   // [d][l]

  s16x8 qf0 = *(const s16x8*)(Qh + (size_t)(q0 + c) * HD + quad * 8);
  s16x8 qf1 = *(const s16x8*)(Qh + (size_t)(q0 + c) * HD + 32 + quad * 8);

  f32x4 zero = {0.f, 0.f, 0.f, 0.f};
  f32x4 o[4];
  float lsum[4] = {0.f, 0.f, 0.f, 0.f};
#pragma unroll
  for (int dc = 0; dc < 4; ++dc) o[dc] = zero;

  const int krow = tid >> 2, kq = tid & 3;              // K staging
  const int vd = tid >> 2, vh = (tid >> 1) & 1, vc0 = (tid & 1) * 8;  // V staging

  for (int k0 = 0; k0 < LL; k0 += 64) {
    __syncthreads();
    {
      const unsigned short* ks = Kh + (size_t)(k0 + krow) * HD + kq * 16;
      uint4 ka = *(const uint4*)ks;
      uint4 kb2 = *(const uint4*)(ks + 8);
      const unsigned short* vs = Vh + (size_t)vd * LL + k0 + vh * 32 + vc0;
      uint4 va = *(const uint4*)vs;        // keys [h*32+vc0, +8)
      uint4 vb = *(const uint4*)(vs + 16); // keys [h*32+16+vc0, +8)
      *(uint4*)&Kl[krow][kq * 16] = ka;
      *(uint4*)&Kl[krow][kq * 16 + 8] = kb2;
      const unsigned* ap = (const unsigned*)&va;
      const unsigned* bp = (const unsigned*)&vb;
      unsigned ov[8];
#pragma unroll
      for (int j = 0; j < 4; ++j) {        // interleave (key c, key c+16) pairs
        ov[2 * j]     = __builtin_amdgcn_perm(bp[j], ap[j], 0x05040100u);
        ov[2 * j + 1] = __builtin_amdgcn_perm(bp[j], ap[j], 0x07060302u);
      }
      uint4 w0 = {ov[0], ov[1], ov[2], ov[3]};
      uint4 w1 = {ov[4], ov[5], ov[6], ov[7]};
      *(uint4*)&Vtl[vd][vh * 32 + vc0 * 2] = w0;
      *(uint4*)&Vtl[vd][vh * 32 + vc0 * 2 + 8] = w1;
    }
    __syncthreads();

    // S = Q K^T : 4 col-tiles of 16 keys (key = t*16 + c)
    f32x4 s[4];
#pragma unroll
    for (int t = 0; t < 4; ++t) {
      s16x8 kfa = *(const s16x8*)&Kl[t * 16 + c][quad * 8];
      s16x8 kfb = *(const s16x8*)&Kl[t * 16 + c][32 + quad * 8];
      s[t] = __builtin_amdgcn_mfma_f32_16x16x32_bf16(qf0, kfa, zero, 0, 0, 0);
      s[t] = __builtin_amdgcn_mfma_f32_16x16x32_bf16(qf1, kfb, s[t], 0, 0, 0);
    }

    // p = exp2(s); store packed pairs in interleaved key order; defer l-reduce
#pragma unroll
    for (int r = 0; r < 4; ++r) {
      float p0 = xexp2(s[0][r]);
      float p1 = xexp2(s[1][r]);
      float p2 = xexp2(s[2][r]);
      float p3 = xexp2(s[3][r]);
      lsum[r] += (p0 + p1) + (p2 + p3);
      // RTZ bf16 pack via byte-perm (1 instr per pair)
      unsigned pk01 = __builtin_amdgcn_perm(__float_as_uint(p1), __float_as_uint(p0), 0x07060302u);
      unsigned pk23 = __builtin_amdgcn_perm(__float_as_uint(p3), __float_as_uint(p2), 0x07060302u);
      int row = quad * 4 + r;
      *(unsigned*)&Pl[w][row][2 * c] = pk01;
      *(unsigned*)&Pl[w][row][32 + 2 * c] = pk23;
    }
    asm volatile("s_waitcnt lgkmcnt(0)" ::: "memory");  // P visible to own wave

    // O += P V (both operands in interleaved key order)
#pragma unroll
    for (int kk = 0; kk < 2; ++kk) {
      s16x8 pf = *(const s16x8*)&Pl[w][c][kk * 32 + quad * 8];
#pragma unroll
      for (int dc = 0; dc < 4; ++dc) {
        s16x8 vf = *(const s16x8*)&Vtl[dc * 16 + c][kk * 32 + quad * 8];
        o[dc] = __builtin_amdgcn_mfma_f32_16x16x32_bf16(pf, vf, o[dc], 0, 0, 0);
      }
    }
  }

  // epilogue: reduce l across the 16 c-lanes, normalize, write AO [B,L,DIM]
  const int bi = bh >> 4, h = bh & 15;
#pragma unroll
  for (int r = 0; r < 4; ++r) {
    float l = lsum[r];
    l += __shfl_xor(l, 1);
    l += __shfl_xor(l, 2);
    l += __shfl_xor(l, 4);
    l += __shfl_xor(l, 8);
    float inv = 1.0f / l;
    int li = q0 + quad * 4 + r;
#pragma unroll
    for (int dc = 0; dc < 4; ++dc)
      AO[((size_t)bi * LL + li) * DIMN + h * HD + dc * 16 + c] = f2bf(o[dc][r] * inv);
  }
}

// ---------------- output projection (bf16 weights) ----------------
__global__ __launch_bounds__(64) void o_proj_b(
    const unsigned short* __restrict__ A, const unsigned short* __restrict__ Wob,
    float* __restrict__ Out) {
  const int m0 = blockIdx.x * 64, n0 = blockIdx.y * 64;
  const int lane = threadIdx.x;
  const int c = lane & 15, quad = lane >> 4;

  f32x4 zero = {0.f, 0.f, 0.f, 0.f};
  f32x4 acc[4][4];
#pragma unroll
  for (int i = 0; i < 4; ++i)
#pragma unroll
    for (int j = 0; j < 4; ++j) acc[i][j] = zero;

  const unsigned short* ab = A + (size_t)(m0 + c) * DIMN + quad * 8;
  const unsigned short* bb = Wob + (size_t)(n0 + c) * DIMN + quad * 8;

  for (int k0 = 0; k0 < DIMN; k0 += 32) {
    s16x8 a[4], b[4];
#pragma unroll
    for (int i = 0; i < 4; ++i) a[i] = *(const s16x8*)(ab + i * 16 * DIMN + k0);
#pragma unroll
    for (int j = 0; j < 4; ++j) b[j] = *(const s16x8*)(bb + j * 16 * DIMN + k0);
#pragma unroll
    for (int i = 0; i < 4; ++i)
#pragma unroll
      for (int j = 0; j < 4; ++j)
        acc[i][j] = __builtin_amdgcn_mfma_f32_16x16x32_bf16(a[i], b[j], acc[i][j], 0, 0, 0);
  }

#pragma unroll
  for (int i = 0; i < 4; ++i)
#pragma unroll
    for (int j = 0; j < 4; ++j)
#pragma unroll
      for (int r = 0; r < 4; ++r)
        Out[(size_t)(m0 + i * 16 + quad * 4 + r) * DIMN + n0 + j * 16 + c] = acc[i][j][r];
}

// ---------------- output projection (fp32-weight fallback) ----------------
__global__ __launch_bounds__(64) void o_proj_f(
    const unsigned short* __restrict__ A, const float* __restrict__ Wo,
    float* __restrict__ Out) {
  const int m0 = blockIdx.x * 64, n0 = blockIdx.y * 64;
  const int lane = threadIdx.x;
  const int c = lane & 15, quad = lane >> 4;

  f32x4 zero = {0.f, 0.f, 0.f, 0.f};
  f32x4 acc[4][4];
#pragma unroll
  for (int i = 0; i < 4; ++i)
#pragma unroll
    for (int j = 0; j < 4; ++j) acc[i][j] = zero;

  const unsigned short* ab = A + (size_t)(m0 + c) * DIMN + quad * 8;
  const float* bb = Wo + (size_t)(n0 + c) * DIMN + quad * 8;

  for (int k0 = 0; k0 < DIMN; k0 += 32) {
    s16x8 a[4], b[4];
#pragma unroll
    for (int i = 0; i < 4; ++i) a[i] = *(const s16x8*)(ab + i * 16 * DIMN + k0);
#pragma unroll
    for (int j = 0; j < 4; ++j) {
      const float* p = bb + j * 16 * DIMN + k0;
      b[j] = cvt8(*(const float4*)p, *(const float4*)(p + 4));
    }
#pragma unroll
    for (int i = 0; i < 4; ++i)
#pragma unroll
      for (int j = 0; j < 4; ++j)
        acc[i][j] = __builtin_amdgcn_mfma_f32_16x16x32_bf16(a[i], b[j], acc[i][j], 0, 0, 0);
  }

#pragma unroll
  for (int i = 0; i < 4; ++i)
#pragma unroll
    for (int j = 0; j < 4; ++j)
#pragma unroll
      for (int r = 0; r < 4; ++r)
        Out[(size_t)(m0 + i * 16 + quad * 4 + r) * DIMN + n0 + j * 16 + c] = acc[i][j][r];
}

extern "C" void kernel_launch(void* const* d_in, const int* in_sizes, int n_in,
                              void* d_out, int out_size, void* d_ws, size_t ws_size,
                              hipStream_t stream) {
  const float* X = (const float*)d_in[0];
  const float* Wq = (const float*)d_in[1];
  const float* Wk = (const float*)d_in[2];
  const float* Wv = (const float*)d_in[3];
  const float* Wo = (const float*)d_in[4];
  float* Out = (float*)d_out;

  const size_t M1 = (size_t)1 << 20;
  unsigned short* ws16 = (unsigned short*)d_ws;

  if (ws_size >= (size_t)48 * 1024 * 1024) {
    unsigned short* Xb = ws16;            // 4M elems
    unsigned short* Wb = ws16 + 4 * M1;   // 4 x 1M (Wq,Wk,Wv,Wo)
    unsigned short* Qb = ws16 + 8 * M1;
    unsigned short* Kb = ws16 + 12 * M1;
    unsigned short* VT = ws16 + 16 * M1;
    unsigned short* AO = ws16 + 20 * M1;
    cvt_all<<<dim3(2048, 5), 256, 0, stream>>>(X, Wq, Wk, Wv, Wo, ws16);
    qkv_proj_b<<<dim3(64, 48), 64, 0, stream>>>(Xb, Wb, Qb, Kb, VT);
    attn2<<<dim3(LL / 64, BB * NH), 256, 0, stream>>>(Qb, Kb, VT, AO);
    o_proj_b<<<dim3(64, 16), 64, 0, stream>>>(AO, Wb + 3 * M1, Out);
  } else {
    unsigned short* Qb = ws16;
    unsigned short* Kb = ws16 + 4 * M1;
    unsigned short* VT = ws16 + 8 * M1;
    unsigned short* AO = ws16 + 12 * M1;
    qkv_proj_f<<<dim3(64, 48), 64, 0, stream>>>(X, Wq, Wk, Wv, Qb, Kb, VT);
    attn2<<<dim3(LL / 64, BB * NH), 256, 0, stream>>>(Qb, Kb, VT, AO);
    o_proj_f<<<dim3(64, 16), 64, 0, stream>>>(AO, Wo, Out);
  }
}

// Round 3
// 210.442 us; speedup vs baseline: 2.4217x; 1.3092x over previous
//
#include <hip/hip_runtime.h>

// MultiHeadAttention: out = softmax((XWq^T)(XWk^T)^T / 8) (XWv^T) Wo^T
// B=2, L=2048, DIM=1024, H=16, D=64. fp32 in/out, bf16 MFMA compute.
//
// R3: projections rewritten as m97-style LDS-staged GEMM (128x128 tile, BK=32,
//     global_load_lds width=16, ds_read_b128 fragments). qkv is one fused
//     C[4096][3072] GEMM over contiguous [Wq|Wk|Wv]; V tiles use operand-
//     swapped MFMA to emit V^T directly. attn2 / cvt_all unchanged from R2.

#define DIMN 1024
#define NH 16
#define HD 64
#define BB 2
#define LL 2048

typedef float f32x4 __attribute__((ext_vector_type(4)));
typedef short s16x8 __attribute__((ext_vector_type(8)));

#define QSCALE 0.18033688011112042f  // log2(e)/8, folds softmax exp2 domain

static __device__ __forceinline__ unsigned short f2bf(float f) {
  unsigned u = __float_as_uint(f);
  u += 0x7fffu + ((u >> 16) & 1u);   // RNE
  return (unsigned short)(u >> 16);
}
static __device__ __forceinline__ unsigned packbf2(float lo, float hi) {
  return (unsigned)f2bf(lo) | ((unsigned)f2bf(hi) << 16);
}
static __device__ __forceinline__ float xexp2(float x) {
#if __has_builtin(__builtin_amdgcn_exp2f)
  return __builtin_amdgcn_exp2f(x);
#else
  return exp2f(x);
#endif
}
static __device__ __forceinline__ s16x8 cvt8(float4 a, float4 b) {
  s16x8 r;
  r[0] = (short)f2bf(a.x); r[1] = (short)f2bf(a.y);
  r[2] = (short)f2bf(a.z); r[3] = (short)f2bf(a.w);
  r[4] = (short)f2bf(b.x); r[5] = (short)f2bf(b.y);
  r[6] = (short)f2bf(b.z); r[7] = (short)f2bf(b.w);
  return r;
}
// async global->LDS, 16B/lane; LDS dest is wave-uniform base + lane*16
static __device__ __forceinline__ void gld16(const unsigned short* g,
                                             unsigned short* l) {
#if __has_builtin(__builtin_amdgcn_global_load_lds)
  __builtin_amdgcn_global_load_lds(
      (const __attribute__((address_space(1))) void*)g,
      (__attribute__((address_space(3))) void*)l, 16, 0, 0);
#else
  // fallback: synchronous copy (correct, slower)
  ((uint4*)l)[threadIdx.x & 63] = ((const uint4*)g)[0];
#endif
}

// ---------------- fp32 -> bf16 pre-convert (X + 4 weights) ----------------
// out layout: Xb[0,4M) Wq[4M,5M) Wk[5M,6M) Wv[6M,7M) Wo[7M,8M)
__global__ __launch_bounds__(256) void cvt_all(
    const float* __restrict__ X, const float* __restrict__ Wq,
    const float* __restrict__ Wk, const float* __restrict__ Wv,
    const float* __restrict__ Wo, unsigned short* __restrict__ out) {
  const int seg = blockIdx.y;
  const float* src;
  unsigned short* dst;
  size_t n;
  if (seg == 0) { src = X; dst = out; n = (size_t)1 << 22; }
  else {
    src = (seg == 1) ? Wq : (seg == 2) ? Wk : (seg == 3) ? Wv : Wo;
    dst = out + ((size_t)1 << 22) + (size_t)(seg - 1) * (1u << 20);
    n = (size_t)1 << 20;
  }
  size_t i = ((size_t)blockIdx.x * 256 + threadIdx.x) * 8;
  if (i >= n) return;
  float4 v0 = *(const float4*)(src + i);
  float4 v1 = *(const float4*)(src + i + 4);
  uint4 o;
  o.x = packbf2(v0.x, v0.y); o.y = packbf2(v0.z, v0.w);
  o.z = packbf2(v1.x, v1.y); o.w = packbf2(v1.z, v1.w);
  *(uint4*)(dst + i) = o;
}

// ---------------- fused QKV projection, 128x128 LDS-staged ----------------
// grid (32, 24), block 256 (4 waves; wave owns a 64x64 quadrant).
// C[4096][3072] = Xb * [Wq|Wk|Wv]^T. sel = n0g>>10 picks output tensor.
// sel 0: Q [B,H,L,D] * log2e/8; sel 1: K [B,H,L,D];
// sel 2: operand-swapped MFMA -> V^T stored [B,H,D,L].
__global__ __launch_bounds__(256) void gemm_qkv(
    const unsigned short* __restrict__ Xb, const unsigned short* __restrict__ Wb,
    unsigned short* __restrict__ Qb, unsigned short* __restrict__ Kb,
    unsigned short* __restrict__ VT) {
  __shared__ __align__(16) unsigned short Al[128 * 32];
  __shared__ __align__(16) unsigned short Bl[128 * 32];
  const int m0 = blockIdx.x * 128;
  const int n0g = blockIdx.y * 128;
  const int sel = n0g >> 10;
  const int tid = threadIdx.x;
  const int w = tid >> 6, lane = tid & 63;
  const int c = lane & 15, quad = lane >> 4;
  const int wm = (w & 1) * 64, wn = (w >> 1) * 64;

  f32x4 zero = {0.f, 0.f, 0.f, 0.f};
  f32x4 acc[4][4];
#pragma unroll
  for (int i = 0; i < 4; ++i)
#pragma unroll
    for (int j = 0; j < 4; ++j) acc[i][j] = zero;

  // staging: wave w owns rows [w*32, w*32+32) of each 128x32 tile
  const int srow = w * 32 + (lane >> 2);
  const int scol = (lane & 3) * 8;
  const unsigned short* gA = Xb + (size_t)(m0 + srow) * DIMN + scol;
  const unsigned short* gB = Wb + (size_t)(n0g + srow) * DIMN + scol;
  unsigned short* lA0 = Al + (w * 32) * 32;
  unsigned short* lA1 = Al + (w * 32 + 16) * 32;
  unsigned short* lB0 = Bl + (w * 32) * 32;
  unsigned short* lB1 = Bl + (w * 32 + 16) * 32;

  for (int k0 = 0; k0 < DIMN; k0 += 32) {
    __syncthreads();
    gld16(gA + k0, lA0);
    gld16(gA + k0 + 16 * DIMN, lA1);
    gld16(gB + k0, lB0);
    gld16(gB + k0 + 16 * DIMN, lB1);
    __syncthreads();
    s16x8 a[4], b[4];
#pragma unroll
    for (int i = 0; i < 4; ++i)
      a[i] = *(const s16x8*)&Al[(wm + i * 16 + c) * 32 + quad * 8];
#pragma unroll
    for (int j = 0; j < 4; ++j)
      b[j] = *(const s16x8*)&Bl[(wn + j * 16 + c) * 32 + quad * 8];
    if (sel != 2) {
#pragma unroll
      for (int i = 0; i < 4; ++i)
#pragma unroll
        for (int j = 0; j < 4; ++j)
          acc[i][j] = __builtin_amdgcn_mfma_f32_16x16x32_bf16(a[i], b[j], acc[i][j], 0, 0, 0);
    } else {
#pragma unroll
      for (int i = 0; i < 4; ++i)
#pragma unroll
        for (int j = 0; j < 4; ++j)  // swapped -> C^T in regs
          acc[i][j] = __builtin_amdgcn_mfma_f32_16x16x32_bf16(b[j], a[i], acc[i][j], 0, 0, 0);
    }
  }

  const int n0 = n0g & 1023;
  if (sel != 2) {
    unsigned short* Out = (sel == 0) ? Qb : Kb;
    const float scale = (sel == 0) ? QSCALE : 1.0f;
#pragma unroll
    for (int i = 0; i < 4; ++i)
#pragma unroll
      for (int j = 0; j < 4; ++j)
#pragma unroll
        for (int r = 0; r < 4; ++r) {
          int row = m0 + wm + i * 16 + quad * 4 + r;  // 0..4095 -> bi, li
          int col = n0 + wn + j * 16 + c;             // 0..1023 -> h, d
          Out[(((size_t)(row >> 11) * NH + (col >> 6)) * LL + (row & 2047)) * HD + (col & 63)] =
              f2bf(acc[i][j][r] * scale);
        }
  } else {
#pragma unroll
    for (int i = 0; i < 4; ++i)
#pragma unroll
      for (int j = 0; j < 4; ++j)
#pragma unroll
        for (int r = 0; r < 4; ++r) {
          int n = n0 + wn + j * 16 + quad * 4 + r;    // 0..1023 -> h, d
          int m = m0 + wm + i * 16 + c;               // 0..4095 -> bi, li
          VT[(((size_t)(m >> 11) * NH + (n >> 6)) * HD + (n & 63)) * LL + (m & 2047)] =
              f2bf(acc[i][j][r]);
        }
  }
}

// ---------------- output projection, 128x128 LDS-staged ----------------
// grid (32, 8). Out[4096][1024] fp32 = AO(bf16) * Wo^T.
__global__ __launch_bounds__(256) void gemm_o(
    const unsigned short* __restrict__ A, const unsigned short* __restrict__ Wob,
    float* __restrict__ Out) {
  __shared__ __align__(16) unsigned short Al[128 * 32];
  __shared__ __align__(16) unsigned short Bl[128 * 32];
  const int m0 = blockIdx.x * 128;
  const int n0 = blockIdx.y * 128;
  const int tid = threadIdx.x;
  const int w = tid >> 6, lane = tid & 63;
  const int c = lane & 15, quad = lane >> 4;
  const int wm = (w & 1) * 64, wn = (w >> 1) * 64;

  f32x4 zero = {0.f, 0.f, 0.f, 0.f};
  f32x4 acc[4][4];
#pragma unroll
  for (int i = 0; i < 4; ++i)
#pragma unroll
    for (int j = 0; j < 4; ++j) acc[i][j] = zero;

  const int srow = w * 32 + (lane >> 2);
  const int scol = (lane & 3) * 8;
  const unsigned short* gA = A + (size_t)(m0 + srow) * DIMN + scol;
  const unsigned short* gB = Wob + (size_t)(n0 + srow) * DIMN + scol;
  unsigned short* lA0 = Al + (w * 32) * 32;
  unsigned short* lA1 = Al + (w * 32 + 16) * 32;
  unsigned short* lB0 = Bl + (w * 32) * 32;
  unsigned short* lB1 = Bl + (w * 32 + 16) * 32;

  for (int k0 = 0; k0 < DIMN; k0 += 32) {
    __syncthreads();
    gld16(gA + k0, lA0);
    gld16(gA + k0 + 16 * DIMN, lA1);
    gld16(gB + k0, lB0);
    gld16(gB + k0 + 16 * DIMN, lB1);
    __syncthreads();
    s16x8 a[4], b[4];
#pragma unroll
    for (int i = 0; i < 4; ++i)
      a[i] = *(const s16x8*)&Al[(wm + i * 16 + c) * 32 + quad * 8];
#pragma unroll
    for (int j = 0; j < 4; ++j)
      b[j] = *(const s16x8*)&Bl[(wn + j * 16 + c) * 32 + quad * 8];
#pragma unroll
    for (int i = 0; i < 4; ++i)
#pragma unroll
      for (int j = 0; j < 4; ++j)
        acc[i][j] = __builtin_amdgcn_mfma_f32_16x16x32_bf16(a[i], b[j], acc[i][j], 0, 0, 0);
  }

#pragma unroll
  for (int i = 0; i < 4; ++i)
#pragma unroll
    for (int j = 0; j < 4; ++j)
#pragma unroll
      for (int r = 0; r < 4; ++r)
        Out[(size_t)(m0 + wm + i * 16 + quad * 4 + r) * DIMN + n0 + wn + j * 16 + c] =
            acc[i][j][r];
}

// ---------------- fused QKV projection (fp32 fallback, 1-wave) ----------------
__global__ __launch_bounds__(64) void qkv_proj_f(
    const float* __restrict__ X, const float* __restrict__ Wq,
    const float* __restrict__ Wk, const float* __restrict__ Wv,
    unsigned short* __restrict__ Qb, unsigned short* __restrict__ Kb,
    unsigned short* __restrict__ VT) {
  const int m0 = blockIdx.x * 64;
  const int n0g = blockIdx.y * 64;
  const int sel = n0g >> 10;
  const int n0 = n0g & 1023;
  const float* W = (sel == 0) ? Wq : (sel == 1) ? Wk : Wv;
  const int lane = threadIdx.x;
  const int c = lane & 15, quad = lane >> 4;

  f32x4 zero = {0.f, 0.f, 0.f, 0.f};
  f32x4 acc[4][4];
#pragma unroll
  for (int i = 0; i < 4; ++i)
#pragma unroll
    for (int j = 0; j < 4; ++j) acc[i][j] = zero;

  const float* ab = X + (size_t)(m0 + c) * DIMN + quad * 8;
  const float* bb = W + (size_t)(n0 + c) * DIMN + quad * 8;

  for (int k0 = 0; k0 < DIMN; k0 += 32) {
    s16x8 a[4], b[4];
#pragma unroll
    for (int i = 0; i < 4; ++i) {
      const float* p = ab + i * 16 * DIMN + k0;
      a[i] = cvt8(*(const float4*)p, *(const float4*)(p + 4));
    }
#pragma unroll
    for (int j = 0; j < 4; ++j) {
      const float* p = bb + j * 16 * DIMN + k0;
      b[j] = cvt8(*(const float4*)p, *(const float4*)(p + 4));
    }
    if (sel != 2) {
#pragma unroll
      for (int i = 0; i < 4; ++i)
#pragma unroll
        for (int j = 0; j < 4; ++j)
          acc[i][j] = __builtin_amdgcn_mfma_f32_16x16x32_bf16(a[i], b[j], acc[i][j], 0, 0, 0);
    } else {
#pragma unroll
      for (int i = 0; i < 4; ++i)
#pragma unroll
        for (int j = 0; j < 4; ++j)
          acc[i][j] = __builtin_amdgcn_mfma_f32_16x16x32_bf16(b[j], a[i], acc[i][j], 0, 0, 0);
    }
  }

  if (sel != 2) {
    unsigned short* Out = (sel == 0) ? Qb : Kb;
    const float scale = (sel == 0) ? QSCALE : 1.0f;
#pragma unroll
    for (int i = 0; i < 4; ++i)
#pragma unroll
      for (int j = 0; j < 4; ++j)
#pragma unroll
        for (int r = 0; r < 4; ++r) {
          int row = m0 + i * 16 + quad * 4 + r;
          int nl = n0 + j * 16 + c;
          int bi = row >> 11, li = row & 2047;
          int h = nl >> 6, d = nl & 63;
          Out[(((size_t)bi * NH + h) * LL + li) * HD + d] = f2bf(acc[i][j][r] * scale);
        }
  } else {
#pragma unroll
    for (int i = 0; i < 4; ++i)
#pragma unroll
      for (int j = 0; j < 4; ++j)
#pragma unroll
        for (int r = 0; r < 4; ++r) {
          int n = n0 + j * 16 + quad * 4 + r;
          int l = m0 + i * 16 + c;
          int h = n >> 6, d = n & 63;
          int bi = l >> 11, li = l & 2047;
          VT[(((size_t)bi * NH + h) * HD + d) * LL + li] = f2bf(acc[i][j][r]);
        }
  }
}

// ---------------- flash attention, no-max softmax (unchanged R2) ----------------
__global__ __launch_bounds__(256) void attn2(
    const unsigned short* __restrict__ Qb, const unsigned short* __restrict__ Kb,
    const unsigned short* __restrict__ VT, unsigned short* __restrict__ AO) {
  __shared__ __align__(16) unsigned short Kl[64][72];     // key x d
  __shared__ __align__(16) unsigned short Vtl[64][72];    // d x p(interleaved key)
  __shared__ __align__(16) unsigned short Pl[4][16][72];  // per wave: qrow x p

  const int bh = blockIdx.y;
  const int tid = threadIdx.x;
  const int w = tid >> 6, lane = tid & 63;
  const int c = lane & 15, quad = lane >> 4;
  const int q0 = blockIdx.x * 64 + w * 16;

  const unsigned short* Qh = Qb + (size_t)bh * LL * HD;
  const unsigned short* Kh = Kb + (size_t)bh * LL * HD;
  const unsigned short* Vh = VT + (size_t)bh * HD * LL;   // [d][l]

  s16x8 qf0 = *(const s16x8*)(Qh + (size_t)(q0 + c) * HD + quad * 8);
  s16x8 qf1 = *(const s16x8*)(Qh + (size_t)(q0 + c) * HD + 32 + quad * 8);

  f32x4 zero = {0.f, 0.f, 0.f, 0.f};
  f32x4 o[4];
  float lsum[4] = {0.f, 0.f, 0.f, 0.f};
#pragma unroll
  for (int dc = 0; dc < 4; ++dc) o[dc] = zero;

  const int krow = tid >> 2, kq = tid & 3;
  const int vd = tid >> 2, vh = (tid >> 1) & 1, vc0 = (tid & 1) * 8;

  for (int k0 = 0; k0 < LL; k0 += 64) {
    __syncthreads();
    {
      const unsigned short* ks = Kh + (size_t)(k0 + krow) * HD + kq * 16;
      uint4 ka = *(const uint4*)ks;
      uint4 kb2 = *(const uint4*)(ks + 8);
      const unsigned short* vs = Vh + (size_t)vd * LL + k0 + vh * 32 + vc0;
      uint4 va = *(const uint4*)vs;
      uint4 vb = *(const uint4*)(vs + 16);
      *(uint4*)&Kl[krow][kq * 16] = ka;
      *(uint4*)&Kl[krow][kq * 16 + 8] = kb2;
      const unsigned* ap = (const unsigned*)&va;
      const unsigned* bp = (const unsigned*)&vb;
      unsigned ov[8];
#pragma unroll
      for (int j = 0; j < 4; ++j) {
        ov[2 * j]     = __builtin_amdgcn_perm(bp[j], ap[j], 0x05040100u);
        ov[2 * j + 1] = __builtin_amdgcn_perm(bp[j], ap[j], 0x07060302u);
      }
      uint4 w0 = {ov[0], ov[1], ov[2], ov[3]};
      uint4 w1 = {ov[4], ov[5], ov[6], ov[7]};
      *(uint4*)&Vtl[vd][vh * 32 + vc0 * 2] = w0;
      *(uint4*)&Vtl[vd][vh * 32 + vc0 * 2 + 8] = w1;
    }
    __syncthreads();

    f32x4 s[4];
#pragma unroll
    for (int t = 0; t < 4; ++t) {
      s16x8 kfa = *(const s16x8*)&Kl[t * 16 + c][quad * 8];
      s16x8 kfb = *(const s16x8*)&Kl[t * 16 + c][32 + quad * 8];
      s[t] = __builtin_amdgcn_mfma_f32_16x16x32_bf16(qf0, kfa, zero, 0, 0, 0);
      s[t] = __builtin_amdgcn_mfma_f32_16x16x32_bf16(qf1, kfb, s[t], 0, 0, 0);
    }

#pragma unroll
    for (int r = 0; r < 4; ++r) {
      float p0 = xexp2(s[0][r]);
      float p1 = xexp2(s[1][r]);
      float p2 = xexp2(s[2][r]);
      float p3 = xexp2(s[3][r]);
      lsum[r] += (p0 + p1) + (p2 + p3);
      unsigned pk01 = __builtin_amdgcn_perm(__float_as_uint(p1), __float_as_uint(p0), 0x07060302u);
      unsigned pk23 = __builtin_amdgcn_perm(__float_as_uint(p3), __float_as_uint(p2), 0x07060302u);
      int row = quad * 4 + r;
      *(unsigned*)&Pl[w][row][2 * c] = pk01;
      *(unsigned*)&Pl[w][row][32 + 2 * c] = pk23;
    }
    asm volatile("s_waitcnt lgkmcnt(0)" ::: "memory");

#pragma unroll
    for (int kk = 0; kk < 2; ++kk) {
      s16x8 pf = *(const s16x8*)&Pl[w][c][kk * 32 + quad * 8];
#pragma unroll
      for (int dc = 0; dc < 4; ++dc) {
        s16x8 vf = *(const s16x8*)&Vtl[dc * 16 + c][kk * 32 + quad * 8];
        o[dc] = __builtin_amdgcn_mfma_f32_16x16x32_bf16(pf, vf, o[dc], 0, 0, 0);
      }
    }
  }

  const int bi = bh >> 4, h = bh & 15;
#pragma unroll
  for (int r = 0; r < 4; ++r) {
    float l = lsum[r];
    l += __shfl_xor(l, 1);
    l += __shfl_xor(l, 2);
    l += __shfl_xor(l, 4);
    l += __shfl_xor(l, 8);
    float inv = 1.0f / l;
    int li = q0 + quad * 4 + r;
#pragma unroll
    for (int dc = 0; dc < 4; ++dc)
      AO[((size_t)bi * LL + li) * DIMN + h * HD + dc * 16 + c] = f2bf(o[dc][r] * inv);
  }
}

// ---------------- output projection (fp32-weight fallback, 1-wave) ----------------
__global__ __launch_bounds__(64) void o_proj_f(
    const unsigned short* __restrict__ A, const float* __restrict__ Wo,
    float* __restrict__ Out) {
  const int m0 = blockIdx.x * 64, n0 = blockIdx.y * 64;
  const int lane = threadIdx.x;
  const int c = lane & 15, quad = lane >> 4;

  f32x4 zero = {0.f, 0.f, 0.f, 0.f};
  f32x4 acc[4][4];
#pragma unroll
  for (int i = 0; i < 4; ++i)
#pragma unroll
    for (int j = 0; j < 4; ++j) acc[i][j] = zero;

  const unsigned short* ab = A + (size_t)(m0 + c) * DIMN + quad * 8;
  const float* bb = Wo + (size_t)(n0 + c) * DIMN + quad * 8;

  for (int k0 = 0; k0 < DIMN; k0 += 32) {
    s16x8 a[4], b[4];
#pragma unroll
    for (int i = 0; i < 4; ++i) a[i] = *(const s16x8*)(ab + i * 16 * DIMN + k0);
#pragma unroll
    for (int j = 0; j < 4; ++j) {
      const float* p = bb + j * 16 * DIMN + k0;
      b[j] = cvt8(*(const float4*)p, *(const float4*)(p + 4));
    }
#pragma unroll
    for (int i = 0; i < 4; ++i)
#pragma unroll
      for (int j = 0; j < 4; ++j)
        acc[i][j] = __builtin_amdgcn_mfma_f32_16x16x32_bf16(a[i], b[j], acc[i][j], 0, 0, 0);
  }

#pragma unroll
  for (int i = 0; i < 4; ++i)
#pragma unroll
    for (int j = 0; j < 4; ++j)
#pragma unroll
      for (int r = 0; r < 4; ++r)
        Out[(size_t)(m0 + i * 16 + quad * 4 + r) * DIMN + n0 + j * 16 + c] = acc[i][j][r];
}

extern "C" void kernel_launch(void* const* d_in, const int* in_sizes, int n_in,
                              void* d_out, int out_size, void* d_ws, size_t ws_size,
                              hipStream_t stream) {
  const float* X = (const float*)d_in[0];
  const float* Wq = (const float*)d_in[1];
  const float* Wk = (const float*)d_in[2];
  const float* Wv = (const float*)d_in[3];
  const float* Wo = (const float*)d_in[4];
  float* Out = (float*)d_out;

  const size_t M1 = (size_t)1 << 20;
  unsigned short* ws16 = (unsigned short*)d_ws;

  if (ws_size >= (size_t)48 * 1024 * 1024) {
    unsigned short* Xb = ws16;            // 4M elems
    unsigned short* Wb = ws16 + 4 * M1;   // 4 x 1M (Wq,Wk,Wv,Wo contiguous)
    unsigned short* Qb = ws16 + 8 * M1;
    unsigned short* Kb = ws16 + 12 * M1;
    unsigned short* VT = ws16 + 16 * M1;
    unsigned short* AO = ws16 + 20 * M1;
    cvt_all<<<dim3(2048, 5), 256, 0, stream>>>(X, Wq, Wk, Wv, Wo, ws16);
    gemm_qkv<<<dim3(32, 24), 256, 0, stream>>>(Xb, Wb, Qb, Kb, VT);
    attn2<<<dim3(LL / 64, BB * NH), 256, 0, stream>>>(Qb, Kb, VT, AO);
    gemm_o<<<dim3(32, 8), 256, 0, stream>>>(AO, Wb + 3 * M1, Out);
  } else {
    unsigned short* Qb = ws16;
    unsigned short* Kb = ws16 + 4 * M1;
    unsigned short* VT = ws16 + 8 * M1;
    unsigned short* AO = ws16 + 12 * M1;
    qkv_proj_f<<<dim3(64, 48), 64, 0, stream>>>(X, Wq, Wk, Wv, Qb, Kb, VT);
    attn2<<<dim3(LL / 64, BB * NH), 256, 0, stream>>>(Qb, Kb, VT, AO);
    o_proj_f<<<dim3(64, 16), 64, 0, stream>>>(AO, Wo, Out);
  }
}

// Round 4
// 200.970 us; speedup vs baseline: 2.5358x; 1.0471x over previous
//
#include <hip/hip_runtime.h>

// MultiHeadAttention: out = softmax((XWq^T)(XWk^T)^T / 8) (XWv^T) Wo^T
// B=2, L=2048, DIM=1024, H=16, D=64. fp32 in/out, bf16 MFMA compute.
//
// R4: attn3 = 32 q-rows/wave (2 m-tiles) -> 0.625 LDS reads per MFMA (was
//     1.125), grid (16,32); gemm_o retiled 128x64, 512 blocks (2/CU, was 1);
//     cvt_all exact grid. gemm_qkv unchanged (m97 recipe).

#define DIMN 1024
#define NH 16
#define HD 64
#define BB 2
#define LL 2048

typedef float f32x4 __attribute__((ext_vector_type(4)));
typedef short s16x8 __attribute__((ext_vector_type(8)));

#define QSCALE 0.18033688011112042f  // log2(e)/8, folds softmax exp2 domain

static __device__ __forceinline__ unsigned short f2bf(float f) {
  unsigned u = __float_as_uint(f);
  u += 0x7fffu + ((u >> 16) & 1u);   // RNE
  return (unsigned short)(u >> 16);
}
static __device__ __forceinline__ unsigned packbf2(float lo, float hi) {
  return (unsigned)f2bf(lo) | ((unsigned)f2bf(hi) << 16);
}
static __device__ __forceinline__ float xexp2(float x) {
#if __has_builtin(__builtin_amdgcn_exp2f)
  return __builtin_amdgcn_exp2f(x);
#else
  return exp2f(x);
#endif
}
static __device__ __forceinline__ s16x8 cvt8(float4 a, float4 b) {
  s16x8 r;
  r[0] = (short)f2bf(a.x); r[1] = (short)f2bf(a.y);
  r[2] = (short)f2bf(a.z); r[3] = (short)f2bf(a.w);
  r[4] = (short)f2bf(b.x); r[5] = (short)f2bf(b.y);
  r[6] = (short)f2bf(b.z); r[7] = (short)f2bf(b.w);
  return r;
}
// async global->LDS, 16B/lane; LDS dest is wave-uniform base + lane*16
static __device__ __forceinline__ void gld16(const unsigned short* g,
                                             unsigned short* l) {
#if __has_builtin(__builtin_amdgcn_global_load_lds)
  __builtin_amdgcn_global_load_lds(
      (const __attribute__((address_space(1))) void*)g,
      (__attribute__((address_space(3))) void*)l, 16, 0, 0);
#else
  ((uint4*)l)[threadIdx.x & 63] = ((const uint4*)g)[0];
#endif
}

// ---------------- fp32 -> bf16 pre-convert (X + 4 weights) ----------------
// flat grid 4096: blocks [0,2048) = X (4M elems); then 512 blocks per weight.
// out layout: Xb[0,4M) Wq[4M,5M) Wk[5M,6M) Wv[6M,7M) Wo[7M,8M)
__global__ __launch_bounds__(256) void cvt_all(
    const float* __restrict__ X, const float* __restrict__ Wq,
    const float* __restrict__ Wk, const float* __restrict__ Wv,
    const float* __restrict__ Wo, unsigned short* __restrict__ out) {
  const int blk = blockIdx.x;
  const float* src;
  unsigned short* dst;
  size_t off;
  if (blk < 2048) {
    src = X; dst = out; off = (size_t)blk * 2048;
  } else {
    int s = (blk - 2048) >> 9;
    src = (s == 0) ? Wq : (s == 1) ? Wk : (s == 2) ? Wv : Wo;
    dst = out + ((size_t)1 << 22) + (size_t)s * (1u << 20);
    off = (size_t)((blk - 2048) & 511) * 2048;
  }
  size_t i = off + (size_t)threadIdx.x * 8;
  float4 v0 = *(const float4*)(src + i);
  float4 v1 = *(const float4*)(src + i + 4);
  uint4 o;
  o.x = packbf2(v0.x, v0.y); o.y = packbf2(v0.z, v0.w);
  o.z = packbf2(v1.x, v1.y); o.w = packbf2(v1.z, v1.w);
  *(uint4*)(dst + i) = o;
}

// ---------------- fused QKV projection, 128x128 LDS-staged ----------------
// grid (32, 24), block 256 (4 waves; wave owns a 64x64 quadrant).
__global__ __launch_bounds__(256) void gemm_qkv(
    const unsigned short* __restrict__ Xb, const unsigned short* __restrict__ Wb,
    unsigned short* __restrict__ Qb, unsigned short* __restrict__ Kb,
    unsigned short* __restrict__ VT) {
  __shared__ __align__(16) unsigned short Al[128 * 32];
  __shared__ __align__(16) unsigned short Bl[128 * 32];
  const int m0 = blockIdx.x * 128;
  const int n0g = blockIdx.y * 128;
  const int sel = n0g >> 10;
  const int tid = threadIdx.x;
  const int w = tid >> 6, lane = tid & 63;
  const int c = lane & 15, quad = lane >> 4;
  const int wm = (w & 1) * 64, wn = (w >> 1) * 64;

  f32x4 zero = {0.f, 0.f, 0.f, 0.f};
  f32x4 acc[4][4];
#pragma unroll
  for (int i = 0; i < 4; ++i)
#pragma unroll
    for (int j = 0; j < 4; ++j) acc[i][j] = zero;

  const int srow = w * 32 + (lane >> 2);
  const int scol = (lane & 3) * 8;
  const unsigned short* gA = Xb + (size_t)(m0 + srow) * DIMN + scol;
  const unsigned short* gB = Wb + (size_t)(n0g + srow) * DIMN + scol;
  unsigned short* lA0 = Al + (w * 32) * 32;
  unsigned short* lA1 = Al + (w * 32 + 16) * 32;
  unsigned short* lB0 = Bl + (w * 32) * 32;
  unsigned short* lB1 = Bl + (w * 32 + 16) * 32;

  for (int k0 = 0; k0 < DIMN; k0 += 32) {
    __syncthreads();
    gld16(gA + k0, lA0);
    gld16(gA + k0 + 16 * DIMN, lA1);
    gld16(gB + k0, lB0);
    gld16(gB + k0 + 16 * DIMN, lB1);
    __syncthreads();
    s16x8 a[4], b[4];
#pragma unroll
    for (int i = 0; i < 4; ++i)
      a[i] = *(const s16x8*)&Al[(wm + i * 16 + c) * 32 + quad * 8];
#pragma unroll
    for (int j = 0; j < 4; ++j)
      b[j] = *(const s16x8*)&Bl[(wn + j * 16 + c) * 32 + quad * 8];
    if (sel != 2) {
#pragma unroll
      for (int i = 0; i < 4; ++i)
#pragma unroll
        for (int j = 0; j < 4; ++j)
          acc[i][j] = __builtin_amdgcn_mfma_f32_16x16x32_bf16(a[i], b[j], acc[i][j], 0, 0, 0);
    } else {
#pragma unroll
      for (int i = 0; i < 4; ++i)
#pragma unroll
        for (int j = 0; j < 4; ++j)  // swapped -> C^T in regs
          acc[i][j] = __builtin_amdgcn_mfma_f32_16x16x32_bf16(b[j], a[i], acc[i][j], 0, 0, 0);
    }
  }

  const int n0 = n0g & 1023;
  if (sel != 2) {
    unsigned short* Out = (sel == 0) ? Qb : Kb;
    const float scale = (sel == 0) ? QSCALE : 1.0f;
#pragma unroll
    for (int i = 0; i < 4; ++i)
#pragma unroll
      for (int j = 0; j < 4; ++j)
#pragma unroll
        for (int r = 0; r < 4; ++r) {
          int row = m0 + wm + i * 16 + quad * 4 + r;
          int col = n0 + wn + j * 16 + c;
          Out[(((size_t)(row >> 11) * NH + (col >> 6)) * LL + (row & 2047)) * HD + (col & 63)] =
              f2bf(acc[i][j][r] * scale);
        }
  } else {
#pragma unroll
    for (int i = 0; i < 4; ++i)
#pragma unroll
      for (int j = 0; j < 4; ++j)
#pragma unroll
        for (int r = 0; r < 4; ++r) {
          int n = n0 + wn + j * 16 + quad * 4 + r;
          int m = m0 + wm + i * 16 + c;
          VT[(((size_t)(m >> 11) * NH + (n >> 6)) * HD + (n & 63)) * LL + (m & 2047)] =
              f2bf(acc[i][j][r]);
        }
  }
}

// ---------------- output projection, 128x64 LDS-staged ----------------
// grid (32, 16), block 256. Wave owns 64x32 quadrant. 2 blocks/CU.
__global__ __launch_bounds__(256) void gemm_o(
    const unsigned short* __restrict__ A, const unsigned short* __restrict__ Wob,
    float* __restrict__ Out) {
  __shared__ __align__(16) unsigned short Al[128 * 32];
  __shared__ __align__(16) unsigned short Bl[64 * 32];
  const int m0 = blockIdx.x * 128;
  const int n0 = blockIdx.y * 64;
  const int tid = threadIdx.x;
  const int w = tid >> 6, lane = tid & 63;
  const int c = lane & 15, quad = lane >> 4;
  const int wm = (w & 1) * 64, wn = (w >> 1) * 32;

  f32x4 zero = {0.f, 0.f, 0.f, 0.f};
  f32x4 acc[4][2];
#pragma unroll
  for (int i = 0; i < 4; ++i)
#pragma unroll
    for (int j = 0; j < 2; ++j) acc[i][j] = zero;

  const int srow = w * 32 + (lane >> 2);       // A rows: 128 across 4 waves
  const int brow = w * 16 + (lane >> 2);       // B rows: 64 across 4 waves
  const int scol = (lane & 3) * 8;
  const unsigned short* gA = A + (size_t)(m0 + srow) * DIMN + scol;
  const unsigned short* gB = Wob + (size_t)(n0 + brow) * DIMN + scol;
  unsigned short* lA0 = Al + (w * 32) * 32;
  unsigned short* lA1 = Al + (w * 32 + 16) * 32;
  unsigned short* lB0 = Bl + (w * 16) * 32;

  for (int k0 = 0; k0 < DIMN; k0 += 32) {
    __syncthreads();
    gld16(gA + k0, lA0);
    gld16(gA + k0 + 16 * DIMN, lA1);
    gld16(gB + k0, lB0);
    __syncthreads();
    s16x8 a[4], b[2];
#pragma unroll
    for (int i = 0; i < 4; ++i)
      a[i] = *(const s16x8*)&Al[(wm + i * 16 + c) * 32 + quad * 8];
#pragma unroll
    for (int j = 0; j < 2; ++j)
      b[j] = *(const s16x8*)&Bl[(wn + j * 16 + c) * 32 + quad * 8];
#pragma unroll
    for (int i = 0; i < 4; ++i)
#pragma unroll
      for (int j = 0; j < 2; ++j)
        acc[i][j] = __builtin_amdgcn_mfma_f32_16x16x32_bf16(a[i], b[j], acc[i][j], 0, 0, 0);
  }

#pragma unroll
  for (int i = 0; i < 4; ++i)
#pragma unroll
    for (int j = 0; j < 2; ++j)
#pragma unroll
      for (int r = 0; r < 4; ++r)
        Out[(size_t)(m0 + wm + i * 16 + quad * 4 + r) * DIMN + n0 + wn + j * 16 + c] =
            acc[i][j][r];
}

// ---------------- flash attention, 32 q-rows/wave ----------------
// grid (16, B*NH), block 256 (4 waves). Block covers 128 q-rows, 64 keys/iter.
// Key order within a 64-tile is interleaved (p = h*32+2c+t holds key h*32+c+16t);
// P and V LDS tiles share it (key-sum invariant) -> all LDS ops b32/b128.
__global__ __launch_bounds__(256) void attn3(
    const unsigned short* __restrict__ Qb, const unsigned short* __restrict__ Kb,
    const unsigned short* __restrict__ VT, unsigned short* __restrict__ AO) {
  __shared__ __align__(16) unsigned short Kl[64][72];     // key x d
  __shared__ __align__(16) unsigned short Vtl[64][72];    // d x p(interleaved key)
  __shared__ __align__(16) unsigned short Pl[4][32][72];  // per wave: qrow x p

  const int bh = blockIdx.y;
  const int tid = threadIdx.x;
  const int w = tid >> 6, lane = tid & 63;
  const int c = lane & 15, quad = lane >> 4;
  const int q0 = blockIdx.x * 128 + w * 32;

  const unsigned short* Qh = Qb + (size_t)bh * LL * HD;
  const unsigned short* Kh = Kb + (size_t)bh * LL * HD;
  const unsigned short* Vh = VT + (size_t)bh * HD * LL;   // [d][l]

  s16x8 qf[2][2];
#pragma unroll
  for (int m = 0; m < 2; ++m)
#pragma unroll
    for (int f = 0; f < 2; ++f)
      qf[m][f] = *(const s16x8*)(Qh + (size_t)(q0 + m * 16 + c) * HD + f * 32 + quad * 8);

  f32x4 zero = {0.f, 0.f, 0.f, 0.f};
  f32x4 o[2][4];
  float lsum[2][4];
#pragma unroll
  for (int m = 0; m < 2; ++m)
#pragma unroll
    for (int r = 0; r < 4; ++r) lsum[m][r] = 0.f;
#pragma unroll
  for (int m = 0; m < 2; ++m)
#pragma unroll
    for (int dc = 0; dc < 4; ++dc) o[m][dc] = zero;

  const int krow = tid >> 2, kq = tid & 3;
  const int vd = tid >> 2, vh = (tid >> 1) & 1, vc0 = (tid & 1) * 8;

  for (int k0 = 0; k0 < LL; k0 += 64) {
    __syncthreads();
    {
      const unsigned short* ks = Kh + (size_t)(k0 + krow) * HD + kq * 16;
      uint4 ka = *(const uint4*)ks;
      uint4 kb2 = *(const uint4*)(ks + 8);
      const unsigned short* vs = Vh + (size_t)vd * LL + k0 + vh * 32 + vc0;
      uint4 va = *(const uint4*)vs;
      uint4 vb = *(const uint4*)(vs + 16);
      *(uint4*)&Kl[krow][kq * 16] = ka;
      *(uint4*)&Kl[krow][kq * 16 + 8] = kb2;
      const unsigned* ap = (const unsigned*)&va;
      const unsigned* bp = (const unsigned*)&vb;
      unsigned ov[8];
#pragma unroll
      for (int j = 0; j < 4; ++j) {
        ov[2 * j]     = __builtin_amdgcn_perm(bp[j], ap[j], 0x05040100u);
        ov[2 * j + 1] = __builtin_amdgcn_perm(bp[j], ap[j], 0x07060302u);
      }
      uint4 w0 = {ov[0], ov[1], ov[2], ov[3]};
      uint4 w1 = {ov[4], ov[5], ov[6], ov[7]};
      *(uint4*)&Vtl[vd][vh * 32 + vc0 * 2] = w0;
      *(uint4*)&Vtl[vd][vh * 32 + vc0 * 2 + 8] = w1;
    }
    __syncthreads();

    // S = Q K^T : 4 col-tiles of 16 keys, 2 m-tiles (K frags shared across m)
    f32x4 s[2][4];
#pragma unroll
    for (int t = 0; t < 4; ++t) {
      s16x8 kfa = *(const s16x8*)&Kl[t * 16 + c][quad * 8];
      s16x8 kfb = *(const s16x8*)&Kl[t * 16 + c][32 + quad * 8];
#pragma unroll
      for (int m = 0; m < 2; ++m) {
        s[m][t] = __builtin_amdgcn_mfma_f32_16x16x32_bf16(qf[m][0], kfa, zero, 0, 0, 0);
        s[m][t] = __builtin_amdgcn_mfma_f32_16x16x32_bf16(qf[m][1], kfb, s[m][t], 0, 0, 0);
      }
    }

    // p = exp2(s); packed-pair stores in interleaved key order
#pragma unroll
    for (int m = 0; m < 2; ++m)
#pragma unroll
      for (int r = 0; r < 4; ++r) {
        float p0 = xexp2(s[m][0][r]);
        float p1 = xexp2(s[m][1][r]);
        float p2 = xexp2(s[m][2][r]);
        float p3 = xexp2(s[m][3][r]);
        lsum[m][r] += (p0 + p1) + (p2 + p3);
        unsigned pk01 = __builtin_amdgcn_perm(__float_as_uint(p1), __float_as_uint(p0), 0x07060302u);
        unsigned pk23 = __builtin_amdgcn_perm(__float_as_uint(p3), __float_as_uint(p2), 0x07060302u);
        int row = m * 16 + quad * 4 + r;
        *(unsigned*)&Pl[w][row][2 * c] = pk01;
        *(unsigned*)&Pl[w][row][32 + 2 * c] = pk23;
      }
    asm volatile("s_waitcnt lgkmcnt(0)" ::: "memory");  // P visible to own wave

    // O += P V (V frags shared across m-tiles)
#pragma unroll
    for (int kk = 0; kk < 2; ++kk) {
      s16x8 pf0 = *(const s16x8*)&Pl[w][c][kk * 32 + quad * 8];
      s16x8 pf1 = *(const s16x8*)&Pl[w][16 + c][kk * 32 + quad * 8];
#pragma unroll
      for (int dc = 0; dc < 4; ++dc) {
        s16x8 vf = *(const s16x8*)&Vtl[dc * 16 + c][kk * 32 + quad * 8];
        o[0][dc] = __builtin_amdgcn_mfma_f32_16x16x32_bf16(pf0, vf, o[0][dc], 0, 0, 0);
        o[1][dc] = __builtin_amdgcn_mfma_f32_16x16x32_bf16(pf1, vf, o[1][dc], 0, 0, 0);
      }
    }
  }

  // epilogue: reduce l across the 16 c-lanes, normalize, write AO [B,L,DIM]
  const int bi = bh >> 4, h = bh & 15;
#pragma unroll
  for (int m = 0; m < 2; ++m)
#pragma unroll
    for (int r = 0; r < 4; ++r) {
      float l = lsum[m][r];
      l += __shfl_xor(l, 1);
      l += __shfl_xor(l, 2);
      l += __shfl_xor(l, 4);
      l += __shfl_xor(l, 8);
      float inv = 1.0f / l;
      int li = q0 + m * 16 + quad * 4 + r;
#pragma unroll
      for (int dc = 0; dc < 4; ++dc)
        AO[((size_t)bi * LL + li) * DIMN + h * HD + dc * 16 + c] = f2bf(o[m][dc][r] * inv);
    }
}

// ---------------- fp32 fallback path (1-wave GEMMs), ws < 48 MiB ----------------
__global__ __launch_bounds__(64) void qkv_proj_f(
    const float* __restrict__ X, const float* __restrict__ Wq,
    const float* __restrict__ Wk, const float* __restrict__ Wv,
    unsigned short* __restrict__ Qb, unsigned short* __restrict__ Kb,
    unsigned short* __restrict__ VT) {
  const int m0 = blockIdx.x * 64;
  const int n0g = blockIdx.y * 64;
  const int sel = n0g >> 10;
  const int n0 = n0g & 1023;
  const float* W = (sel == 0) ? Wq : (sel == 1) ? Wk : Wv;
  const int lane = threadIdx.x;
  const int c = lane & 15, quad = lane >> 4;

  f32x4 zero = {0.f, 0.f, 0.f, 0.f};
  f32x4 acc[4][4];
#pragma unroll
  for (int i = 0; i < 4; ++i)
#pragma unroll
    for (int j = 0; j < 4; ++j) acc[i][j] = zero;

  const float* ab = X + (size_t)(m0 + c) * DIMN + quad * 8;
  const float* bb = W + (size_t)(n0 + c) * DIMN + quad * 8;

  for (int k0 = 0; k0 < DIMN; k0 += 32) {
    s16x8 a[4], b[4];
#pragma unroll
    for (int i = 0; i < 4; ++i) {
      const float* p = ab + i * 16 * DIMN + k0;
      a[i] = cvt8(*(const float4*)p, *(const float4*)(p + 4));
    }
#pragma unroll
    for (int j = 0; j < 4; ++j) {
      const float* p = bb + j * 16 * DIMN + k0;
      b[j] = cvt8(*(const float4*)p, *(const float4*)(p + 4));
    }
    if (sel != 2) {
#pragma unroll
      for (int i = 0; i < 4; ++i)
#pragma unroll
        for (int j = 0; j < 4; ++j)
          acc[i][j] = __builtin_amdgcn_mfma_f32_16x16x32_bf16(a[i], b[j], acc[i][j], 0, 0, 0);
    } else {
#pragma unroll
      for (int i = 0; i < 4; ++i)
#pragma unroll
        for (int j = 0; j < 4; ++j)
          acc[i][j] = __builtin_amdgcn_mfma_f32_16x16x32_bf16(b[j], a[i], acc[i][j], 0, 0, 0);
    }
  }

  if (sel != 2) {
    unsigned short* Out = (sel == 0) ? Qb : Kb;
    const float scale = (sel == 0) ? QSCALE : 1.0f;
#pragma unroll
    for (int i = 0; i < 4; ++i)
#pragma unroll
      for (int j = 0; j < 4; ++j)
#pragma unroll
        for (int r = 0; r < 4; ++r) {
          int row = m0 + i * 16 + quad * 4 + r;
          int nl = n0 + j * 16 + c;
          int bi = row >> 11, li = row & 2047;
          int h = nl >> 6, d = nl & 63;
          Out[(((size_t)bi * NH + h) * LL + li) * HD + d] = f2bf(acc[i][j][r] * scale);
        }
  } else {
#pragma unroll
    for (int i = 0; i < 4; ++i)
#pragma unroll
      for (int j = 0; j < 4; ++j)
#pragma unroll
        for (int r = 0; r < 4; ++r) {
          int n = n0 + j * 16 + quad * 4 + r;
          int l = m0 + i * 16 + c;
          int h = n >> 6, d = n & 63;
          int bi = l >> 11, li = l & 2047;
          VT[(((size_t)bi * NH + h) * HD + d) * LL + li] = f2bf(acc[i][j][r]);
        }
  }
}

__global__ __launch_bounds__(64) void o_proj_f(
    const unsigned short* __restrict__ A, const float* __restrict__ Wo,
    float* __restrict__ Out) {
  const int m0 = blockIdx.x * 64, n0 = blockIdx.y * 64;
  const int lane = threadIdx.x;
  const int c = lane & 15, quad = lane >> 4;

  f32x4 zero = {0.f, 0.f, 0.f, 0.f};
  f32x4 acc[4][4];
#pragma unroll
  for (int i = 0; i < 4; ++i)
#pragma unroll
    for (int j = 0; j < 4; ++j) acc[i][j] = zero;

  const unsigned short* ab = A + (size_t)(m0 + c) * DIMN + quad * 8;
  const float* bb = Wo + (size_t)(n0 + c) * DIMN + quad * 8;

  for (int k0 = 0; k0 < DIMN; k0 += 32) {
    s16x8 a[4], b[4];
#pragma unroll
    for (int i = 0; i < 4; ++i) a[i] = *(const s16x8*)(ab + i * 16 * DIMN + k0);
#pragma unroll
    for (int j = 0; j < 4; ++j) {
      const float* p = bb + j * 16 * DIMN + k0;
      b[j] = cvt8(*(const float4*)p, *(const float4*)(p + 4));
    }
#pragma unroll
    for (int i = 0; i < 4; ++i)
#pragma unroll
      for (int j = 0; j < 4; ++j)
        acc[i][j] = __builtin_amdgcn_mfma_f32_16x16x32_bf16(a[i], b[j], acc[i][j], 0, 0, 0);
  }

#pragma unroll
  for (int i = 0; i < 4; ++i)
#pragma unroll
    for (int j = 0; j < 4; ++j)
#pragma unroll
      for (int r = 0; r < 4; ++r)
        Out[(size_t)(m0 + i * 16 + quad * 4 + r) * DIMN + n0 + j * 16 + c] = acc[i][j][r];
}

extern "C" void kernel_launch(void* const* d_in, const int* in_sizes, int n_in,
                              void* d_out, int out_size, void* d_ws, size_t ws_size,
                              hipStream_t stream) {
  const float* X = (const float*)d_in[0];
  const float* Wq = (const float*)d_in[1];
  const float* Wk = (const float*)d_in[2];
  const float* Wv = (const float*)d_in[3];
  const float* Wo = (const float*)d_in[4];
  float* Out = (float*)d_out;

  const size_t M1 = (size_t)1 << 20;
  unsigned short* ws16 = (unsigned short*)d_ws;

  if (ws_size >= (size_t)48 * 1024 * 1024) {
    unsigned short* Xb = ws16;            // 4M elems
    unsigned short* Wb = ws16 + 4 * M1;   // 4 x 1M (Wq,Wk,Wv,Wo contiguous)
    unsigned short* Qb = ws16 + 8 * M1;
    unsigned short* Kb = ws16 + 12 * M1;
    unsigned short* VT = ws16 + 16 * M1;
    unsigned short* AO = ws16 + 20 * M1;
    cvt_all<<<4096, 256, 0, stream>>>(X, Wq, Wk, Wv, Wo, ws16);
    gemm_qkv<<<dim3(32, 24), 256, 0, stream>>>(Xb, Wb, Qb, Kb, VT);
    attn3<<<dim3(LL / 128, BB * NH), 256, 0, stream>>>(Qb, Kb, VT, AO);
    gemm_o<<<dim3(32, 16), 256, 0, stream>>>(AO, Wb + 3 * M1, Out);
  } else {
    unsigned short* Qb = ws16;
    unsigned short* Kb = ws16 + 4 * M1;
    unsigned short* VT = ws16 + 8 * M1;
    unsigned short* AO = ws16 + 12 * M1;
    qkv_proj_f<<<dim3(64, 48), 64, 0, stream>>>(X, Wq, Wk, Wv, Qb, Kb, VT);
    attn3<<<dim3(LL / 128, BB * NH), 256, 0, stream>>>(Qb, Kb, VT, AO);
    o_proj_f<<<dim3(64, 16), 64, 0, stream>>>(AO, Wo, Out);
  }
}

// Round 5
// 196.881 us; speedup vs baseline: 2.5885x; 1.0208x over previous
//
#include <hip/hip_runtime.h>

// MultiHeadAttention: out = softmax((XWq^T)(XWk^T)^T / 8) (XWv^T) Wo^T
// B=2, L=2048, DIM=1024, H=16, D=64. fp32 in/out, bf16 MFMA compute.
//
// R5: attn4 stages K/V via global_load_lds into XOR-swizzled unpadded LDS
//     tiles (no VGPR round-trip, no v_perm transpose — VT is pre-interleaved
//     by the projection epilogue); 128-key tiles (half the barriers), P done
//     in two 64-key passes; all hot-loop LDS addresses loop-invariant.

#define DIMN 1024
#define NH 16
#define HD 64
#define BB 2
#define LL 2048

typedef float f32x4 __attribute__((ext_vector_type(4)));
typedef short s16x8 __attribute__((ext_vector_type(8)));

#define QSCALE 0.18033688011112042f  // log2(e)/8, folds softmax exp2 domain

static __device__ __forceinline__ unsigned short f2bf(float f) {
  unsigned u = __float_as_uint(f);
  u += 0x7fffu + ((u >> 16) & 1u);   // RNE
  return (unsigned short)(u >> 16);
}
static __device__ __forceinline__ unsigned packbf2(float lo, float hi) {
  return (unsigned)f2bf(lo) | ((unsigned)f2bf(hi) << 16);
}
static __device__ __forceinline__ float xexp2(float x) {
#if __has_builtin(__builtin_amdgcn_exp2f)
  return __builtin_amdgcn_exp2f(x);
#else
  return exp2f(x);
#endif
}
static __device__ __forceinline__ s16x8 cvt8(float4 a, float4 b) {
  s16x8 r;
  r[0] = (short)f2bf(a.x); r[1] = (short)f2bf(a.y);
  r[2] = (short)f2bf(a.z); r[3] = (short)f2bf(a.w);
  r[4] = (short)f2bf(b.x); r[5] = (short)f2bf(b.y);
  r[6] = (short)f2bf(b.z); r[7] = (short)f2bf(b.w);
  return r;
}
// async global->LDS, 16B/lane; LDS dest is wave-uniform base + lane*16
static __device__ __forceinline__ void gld16(const unsigned short* g,
                                             unsigned short* l) {
#if __has_builtin(__builtin_amdgcn_global_load_lds)
  __builtin_amdgcn_global_load_lds(
      (const __attribute__((address_space(1))) void*)g,
      (__attribute__((address_space(3))) void*)l, 16, 0, 0);
#else
  ((uint4*)l)[threadIdx.x & 63] = ((const uint4*)g)[0];
#endif
}

// interleave map within a 64-seq group (matches attn P-column order):
// key k -> p = (k>>5)*32 + (k&15)*2 + ((k>>4)&1)

// ---------------- fp32 -> bf16 pre-convert (X + 4 weights) ----------------
__global__ __launch_bounds__(256) void cvt_all(
    const float* __restrict__ X, const float* __restrict__ Wq,
    const float* __restrict__ Wk, const float* __restrict__ Wv,
    const float* __restrict__ Wo, unsigned short* __restrict__ out) {
  const int blk = blockIdx.x;
  const float* src;
  unsigned short* dst;
  size_t off;
  if (blk < 2048) {
    src = X; dst = out; off = (size_t)blk * 2048;
  } else {
    int s = (blk - 2048) >> 9;
    src = (s == 0) ? Wq : (s == 1) ? Wk : (s == 2) ? Wv : Wo;
    dst = out + ((size_t)1 << 22) + (size_t)s * (1u << 20);
    off = (size_t)((blk - 2048) & 511) * 2048;
  }
  size_t i = off + (size_t)threadIdx.x * 8;
  float4 v0 = *(const float4*)(src + i);
  float4 v1 = *(const float4*)(src + i + 4);
  uint4 o;
  o.x = packbf2(v0.x, v0.y); o.y = packbf2(v0.z, v0.w);
  o.z = packbf2(v1.x, v1.y); o.w = packbf2(v1.z, v1.w);
  *(uint4*)(dst + i) = o;
}

// ---------------- fused QKV projection, 128x128 LDS-staged ----------------
__global__ __launch_bounds__(256) void gemm_qkv(
    const unsigned short* __restrict__ Xb, const unsigned short* __restrict__ Wb,
    unsigned short* __restrict__ Qb, unsigned short* __restrict__ Kb,
    unsigned short* __restrict__ VT) {
  __shared__ __align__(16) unsigned short Al[128 * 32];
  __shared__ __align__(16) unsigned short Bl[128 * 32];
  const int m0 = blockIdx.x * 128;
  const int n0g = blockIdx.y * 128;
  const int sel = n0g >> 10;
  const int tid = threadIdx.x;
  const int w = tid >> 6, lane = tid & 63;
  const int c = lane & 15, quad = lane >> 4;
  const int wm = (w & 1) * 64, wn = (w >> 1) * 64;

  f32x4 zero = {0.f, 0.f, 0.f, 0.f};
  f32x4 acc[4][4];
#pragma unroll
  for (int i = 0; i < 4; ++i)
#pragma unroll
    for (int j = 0; j < 4; ++j) acc[i][j] = zero;

  const int srow = w * 32 + (lane >> 2);
  const int scol = (lane & 3) * 8;
  const unsigned short* gA = Xb + (size_t)(m0 + srow) * DIMN + scol;
  const unsigned short* gB = Wb + (size_t)(n0g + srow) * DIMN + scol;
  unsigned short* lA0 = Al + (w * 32) * 32;
  unsigned short* lA1 = Al + (w * 32 + 16) * 32;
  unsigned short* lB0 = Bl + (w * 32) * 32;
  unsigned short* lB1 = Bl + (w * 32 + 16) * 32;

  for (int k0 = 0; k0 < DIMN; k0 += 32) {
    __syncthreads();
    gld16(gA + k0, lA0);
    gld16(gA + k0 + 16 * DIMN, lA1);
    gld16(gB + k0, lB0);
    gld16(gB + k0 + 16 * DIMN, lB1);
    __syncthreads();
    s16x8 a[4], b[4];
#pragma unroll
    for (int i = 0; i < 4; ++i)
      a[i] = *(const s16x8*)&Al[(wm + i * 16 + c) * 32 + quad * 8];
#pragma unroll
    for (int j = 0; j < 4; ++j)
      b[j] = *(const s16x8*)&Bl[(wn + j * 16 + c) * 32 + quad * 8];
    if (sel != 2) {
#pragma unroll
      for (int i = 0; i < 4; ++i)
#pragma unroll
        for (int j = 0; j < 4; ++j)
          acc[i][j] = __builtin_amdgcn_mfma_f32_16x16x32_bf16(a[i], b[j], acc[i][j], 0, 0, 0);
    } else {
#pragma unroll
      for (int i = 0; i < 4; ++i)
#pragma unroll
        for (int j = 0; j < 4; ++j)  // swapped -> C^T in regs
          acc[i][j] = __builtin_amdgcn_mfma_f32_16x16x32_bf16(b[j], a[i], acc[i][j], 0, 0, 0);
    }
  }

  const int n0 = n0g & 1023;
  if (sel != 2) {
    unsigned short* Out = (sel == 0) ? Qb : Kb;
    const float scale = (sel == 0) ? QSCALE : 1.0f;
#pragma unroll
    for (int i = 0; i < 4; ++i)
#pragma unroll
      for (int j = 0; j < 4; ++j)
#pragma unroll
        for (int r = 0; r < 4; ++r) {
          int row = m0 + wm + i * 16 + quad * 4 + r;
          int col = n0 + wn + j * 16 + c;
          Out[(((size_t)(row >> 11) * NH + (col >> 6)) * LL + (row & 2047)) * HD + (col & 63)] =
              f2bf(acc[i][j][r] * scale);
        }
  } else {
    // V^T stored [B,H,D,L] with seq index interleaved within each 64-group
#pragma unroll
    for (int i = 0; i < 4; ++i) {
      const int p64 = (i >> 1) * 32 + (i & 1);  // + 2*c below
#pragma unroll
      for (int j = 0; j < 4; ++j)
#pragma unroll
        for (int r = 0; r < 4; ++r) {
          int n = n0 + wn + j * 16 + quad * 4 + r;
          int m = m0 + wm + p64 + 2 * c;
          VT[(((size_t)(m >> 11) * NH + (n >> 6)) * HD + (n & 63)) * LL + (m & 2047)] =
              f2bf(acc[i][j][r]);
        }
    }
  }
}

// ---------------- output projection, 128x64 LDS-staged ----------------
__global__ __launch_bounds__(256) void gemm_o(
    const unsigned short* __restrict__ A, const unsigned short* __restrict__ Wob,
    float* __restrict__ Out) {
  __shared__ __align__(16) unsigned short Al[128 * 32];
  __shared__ __align__(16) unsigned short Bl[64 * 32];
  const int m0 = blockIdx.x * 128;
  const int n0 = blockIdx.y * 64;
  const int tid = threadIdx.x;
  const int w = tid >> 6, lane = tid & 63;
  const int c = lane & 15, quad = lane >> 4;
  const int wm = (w & 1) * 64, wn = (w >> 1) * 32;

  f32x4 zero = {0.f, 0.f, 0.f, 0.f};
  f32x4 acc[4][2];
#pragma unroll
  for (int i = 0; i < 4; ++i)
#pragma unroll
    for (int j = 0; j < 2; ++j) acc[i][j] = zero;

  const int srow = w * 32 + (lane >> 2);
  const int brow = w * 16 + (lane >> 2);
  const int scol = (lane & 3) * 8;
  const unsigned short* gA = A + (size_t)(m0 + srow) * DIMN + scol;
  const unsigned short* gB = Wob + (size_t)(n0 + brow) * DIMN + scol;
  unsigned short* lA0 = Al + (w * 32) * 32;
  unsigned short* lA1 = Al + (w * 32 + 16) * 32;
  unsigned short* lB0 = Bl + (w * 16) * 32;

  for (int k0 = 0; k0 < DIMN; k0 += 32) {
    __syncthreads();
    gld16(gA + k0, lA0);
    gld16(gA + k0 + 16 * DIMN, lA1);
    gld16(gB + k0, lB0);
    __syncthreads();
    s16x8 a[4], b[2];
#pragma unroll
    for (int i = 0; i < 4; ++i)
      a[i] = *(const s16x8*)&Al[(wm + i * 16 + c) * 32 + quad * 8];
#pragma unroll
    for (int j = 0; j < 2; ++j)
      b[j] = *(const s16x8*)&Bl[(wn + j * 16 + c) * 32 + quad * 8];
#pragma unroll
    for (int i = 0; i < 4; ++i)
#pragma unroll
      for (int j = 0; j < 2; ++j)
        acc[i][j] = __builtin_amdgcn_mfma_f32_16x16x32_bf16(a[i], b[j], acc[i][j], 0, 0, 0);
  }

#pragma unroll
  for (int i = 0; i < 4; ++i)
#pragma unroll
    for (int j = 0; j < 2; ++j)
#pragma unroll
      for (int r = 0; r < 4; ++r)
        Out[(size_t)(m0 + wm + i * 16 + quad * 4 + r) * DIMN + n0 + wn + j * 16 + c] =
            acc[i][j][r];
}

// ---------------- flash attention, gld16-staged K/V ----------------
// grid (16, B*NH), block 256 (4 waves x 32 q-rows). 128 keys per K/V tile,
// P handled in two 64-key passes. K tile [key][64d] and V tile [d][128key]
// are XOR-swizzled on 16B chunks (source-side swizzle; conflict-free reads).
// V global is [B,H,D,L] pre-interleaved per 64-group (p = 32h+2c+t).
__global__ __launch_bounds__(256) void attn4(
    const unsigned short* __restrict__ Qb, const unsigned short* __restrict__ Kb,
    const unsigned short* __restrict__ VT, unsigned short* __restrict__ AO) {
  __shared__ __align__(16) unsigned short Kl[128 * 64];    // 16 KB, swizzled
  __shared__ __align__(16) unsigned short Vtl[64 * 128];   // 16 KB, swizzled
  __shared__ __align__(16) unsigned short Pl[4][32][72];   // 18 KB, per-wave P

  const int bh = blockIdx.y;
  const int tid = threadIdx.x;
  const int w = tid >> 6, lane = tid & 63;
  const int c = lane & 15, quad = lane >> 4;
  const int q0 = blockIdx.x * 128 + w * 32;

  const unsigned short* Qh = Qb + (size_t)bh * LL * HD;
  const unsigned short* Kh = Kb + (size_t)bh * LL * HD;
  const unsigned short* Vh = VT + (size_t)bh * HD * LL;   // [d][l], interleaved

  s16x8 qf[2][2];
#pragma unroll
  for (int m = 0; m < 2; ++m)
#pragma unroll
    for (int f = 0; f < 2; ++f)
      qf[m][f] = *(const s16x8*)(Qh + (size_t)(q0 + m * 16 + c) * HD + f * 32 + quad * 8);

  f32x4 zero = {0.f, 0.f, 0.f, 0.f};
  f32x4 o[2][4];
  float lsum[2][4];
#pragma unroll
  for (int m = 0; m < 2; ++m)
#pragma unroll
    for (int r = 0; r < 4; ++r) lsum[m][r] = 0.f;
#pragma unroll
  for (int m = 0; m < 2; ++m)
#pragma unroll
    for (int dc = 0; dc < 4; ++dc) o[m][dc] = zero;

  // --- staging geometry (all loop-invariant) ---
  // K: row = s*32 + w*8 + (lane>>3), phys chunk = lane&7; src col undoes swizzle
  const int l8 = lane >> 3, p8 = lane & 7;
  const unsigned short* gK = Kh + (size_t)(w * 8 + l8) * HD + ((p8 ^ l8) * 8);
  unsigned short* lK = (unsigned short*)Kl + (w * 8) * 64;
  // V: row(d) = s*16 + w*4 + (lane>>4), phys chunk = lane&15
  const int l16 = lane >> 4, p16 = lane & 15;
  const int vrow = w * 4 + l16;  // row&15
  const unsigned short* gV = Vh + (size_t)vrow * LL + ((p16 ^ vrow) * 8);
  unsigned short* lV = (unsigned short*)Vtl + (w * 4) * 128;

  // --- compute-side LDS addresses (loop-invariant) ---
  const int kpa = (quad ^ (c & 7)) * 8;        // kfa phys chunk offset (shorts)
  const int kpb = ((quad + 4) ^ (c & 7)) * 8;  // kfb

  for (int k0 = 0; k0 < LL; k0 += 128) {
    __syncthreads();
#pragma unroll
    for (int s = 0; s < 4; ++s)
      gld16(gK + (size_t)(k0 + s * 32) * HD, lK + s * 32 * 64);
#pragma unroll
    for (int s = 0; s < 4; ++s)
      gld16(gV + (size_t)(s * 16) * LL + k0, lV + s * 16 * 128);
    __syncthreads();

#pragma unroll
    for (int g = 0; g < 2; ++g) {
      // S = Q K^T for keys [g*64, g*64+64)
      f32x4 s[2][4];
#pragma unroll
      for (int t4 = 0; t4 < 4; ++t4) {
        const int t = g * 4 + t4;
        s16x8 kfa = *(const s16x8*)&Kl[(t * 16 + c) * 64 + kpa];
        s16x8 kfb = *(const s16x8*)&Kl[(t * 16 + c) * 64 + kpb];
#pragma unroll
        for (int m = 0; m < 2; ++m) {
          s[m][t4] = __builtin_amdgcn_mfma_f32_16x16x32_bf16(qf[m][0], kfa, zero, 0, 0, 0);
          s[m][t4] = __builtin_amdgcn_mfma_f32_16x16x32_bf16(qf[m][1], kfb, s[m][t4], 0, 0, 0);
        }
      }
      // p = exp2(s), packed pairs in interleaved key order
#pragma unroll
      for (int m = 0; m < 2; ++m)
#pragma unroll
        for (int r = 0; r < 4; ++r) {
          float p0 = xexp2(s[m][0][r]);
          float p1 = xexp2(s[m][1][r]);
          float p2 = xexp2(s[m][2][r]);
          float p3 = xexp2(s[m][3][r]);
          lsum[m][r] += (p0 + p1) + (p2 + p3);
          unsigned pk01 = __builtin_amdgcn_perm(__float_as_uint(p1), __float_as_uint(p0), 0x07060302u);
          unsigned pk23 = __builtin_amdgcn_perm(__float_as_uint(p3), __float_as_uint(p2), 0x07060302u);
          int row = m * 16 + quad * 4 + r;
          *(unsigned*)&Pl[w][row][2 * c] = pk01;
          *(unsigned*)&Pl[w][row][32 + 2 * c] = pk23;
        }
      asm volatile("s_waitcnt lgkmcnt(0)" ::: "memory");  // P visible to own wave

      // O += P V for this 64-key group (V cols g*64 + kh*32)
#pragma unroll
      for (int kh = 0; kh < 2; ++kh) {
        const int kk = g * 2 + kh;
        s16x8 pf0 = *(const s16x8*)&Pl[w][c][kh * 32 + quad * 8];
        s16x8 pf1 = *(const s16x8*)&Pl[w][16 + c][kh * 32 + quad * 8];
#pragma unroll
        for (int dc = 0; dc < 4; ++dc) {
          s16x8 vf = *(const s16x8*)&Vtl[(dc * 16 + c) * 128 + (((kk * 4 + quad) ^ c) * 8)];
          o[0][dc] = __builtin_amdgcn_mfma_f32_16x16x32_bf16(pf0, vf, o[0][dc], 0, 0, 0);
          o[1][dc] = __builtin_amdgcn_mfma_f32_16x16x32_bf16(pf1, vf, o[1][dc], 0, 0, 0);
        }
      }
    }
  }

  // epilogue: reduce l across the 16 c-lanes, normalize, write AO [B,L,DIM]
  const int bi = bh >> 4, h = bh & 15;
#pragma unroll
  for (int m = 0; m < 2; ++m)
#pragma unroll
    for (int r = 0; r < 4; ++r) {
      float l = lsum[m][r];
      l += __shfl_xor(l, 1);
      l += __shfl_xor(l, 2);
      l += __shfl_xor(l, 4);
      l += __shfl_xor(l, 8);
      float inv = 1.0f / l;
      int li = q0 + m * 16 + quad * 4 + r;
#pragma unroll
      for (int dc = 0; dc < 4; ++dc)
        AO[((size_t)bi * LL + li) * DIMN + h * HD + dc * 16 + c] = f2bf(o[m][dc][r] * inv);
    }
}

// ---------------- fp32 fallback path (1-wave GEMMs), ws < 48 MiB ----------------
__global__ __launch_bounds__(64) void qkv_proj_f(
    const float* __restrict__ X, const float* __restrict__ Wq,
    const float* __restrict__ Wk, const float* __restrict__ Wv,
    unsigned short* __restrict__ Qb, unsigned short* __restrict__ Kb,
    unsigned short* __restrict__ VT) {
  const int m0 = blockIdx.x * 64;
  const int n0g = blockIdx.y * 64;
  const int sel = n0g >> 10;
  const int n0 = n0g & 1023;
  const float* W = (sel == 0) ? Wq : (sel == 1) ? Wk : Wv;
  const int lane = threadIdx.x;
  const int c = lane & 15, quad = lane >> 4;

  f32x4 zero = {0.f, 0.f, 0.f, 0.f};
  f32x4 acc[4][4];
#pragma unroll
  for (int i = 0; i < 4; ++i)
#pragma unroll
    for (int j = 0; j < 4; ++j) acc[i][j] = zero;

  const float* ab = X + (size_t)(m0 + c) * DIMN + quad * 8;
  const float* bb = W + (size_t)(n0 + c) * DIMN + quad * 8;

  for (int k0 = 0; k0 < DIMN; k0 += 32) {
    s16x8 a[4], b[4];
#pragma unroll
    for (int i = 0; i < 4; ++i) {
      const float* p = ab + i * 16 * DIMN + k0;
      a[i] = cvt8(*(const float4*)p, *(const float4*)(p + 4));
    }
#pragma unroll
    for (int j = 0; j < 4; ++j) {
      const float* p = bb + j * 16 * DIMN + k0;
      b[j] = cvt8(*(const float4*)p, *(const float4*)(p + 4));
    }
    if (sel != 2) {
#pragma unroll
      for (int i = 0; i < 4; ++i)
#pragma unroll
        for (int j = 0; j < 4; ++j)
          acc[i][j] = __builtin_amdgcn_mfma_f32_16x16x32_bf16(a[i], b[j], acc[i][j], 0, 0, 0);
    } else {
#pragma unroll
      for (int i = 0; i < 4; ++i)
#pragma unroll
        for (int j = 0; j < 4; ++j)
          acc[i][j] = __builtin_amdgcn_mfma_f32_16x16x32_bf16(b[j], a[i], acc[i][j], 0, 0, 0);
    }
  }

  if (sel != 2) {
    unsigned short* Out = (sel == 0) ? Qb : Kb;
    const float scale = (sel == 0) ? QSCALE : 1.0f;
#pragma unroll
    for (int i = 0; i < 4; ++i)
#pragma unroll
      for (int j = 0; j < 4; ++j)
#pragma unroll
        for (int r = 0; r < 4; ++r) {
          int row = m0 + i * 16 + quad * 4 + r;
          int nl = n0 + j * 16 + c;
          int bi = row >> 11, li = row & 2047;
          int h = nl >> 6, d = nl & 63;
          Out[(((size_t)bi * NH + h) * LL + li) * HD + d] = f2bf(acc[i][j][r] * scale);
        }
  } else {
#pragma unroll
    for (int i = 0; i < 4; ++i) {
      const int p64 = (i >> 1) * 32 + (i & 1);
#pragma unroll
      for (int j = 0; j < 4; ++j)
#pragma unroll
        for (int r = 0; r < 4; ++r) {
          int n = n0 + j * 16 + quad * 4 + r;
          int l = m0 + p64 + 2 * c;
          int h = n >> 6, d = n & 63;
          int bi = l >> 11, li = l & 2047;
          VT[(((size_t)bi * NH + h) * HD + d) * LL + li] = f2bf(acc[i][j][r]);
        }
    }
  }
}

__global__ __launch_bounds__(64) void o_proj_f(
    const unsigned short* __restrict__ A, const float* __restrict__ Wo,
    float* __restrict__ Out) {
  const int m0 = blockIdx.x * 64, n0 = blockIdx.y * 64;
  const int lane = threadIdx.x;
  const int c = lane & 15, quad = lane >> 4;

  f32x4 zero = {0.f, 0.f, 0.f, 0.f};
  f32x4 acc[4][4];
#pragma unroll
  for (int i = 0; i < 4; ++i)
#pragma unroll
    for (int j = 0; j < 4; ++j) acc[i][j] = zero;

  const unsigned short* ab = A + (size_t)(m0 + c) * DIMN + quad * 8;
  const float* bb = Wo + (size_t)(n0 + c) * DIMN + quad * 8;

  for (int k0 = 0; k0 < DIMN; k0 += 32) {
    s16x8 a[4], b[4];
#pragma unroll
    for (int i = 0; i < 4; ++i) a[i] = *(const s16x8*)(ab + i * 16 * DIMN + k0);
#pragma unroll
    for (int j = 0; j < 4; ++j) {
      const float* p = bb + j * 16 * DIMN + k0;
      b[j] = cvt8(*(const float4*)p, *(const float4*)(p + 4));
    }
#pragma unroll
    for (int i = 0; i < 4; ++i)
#pragma unroll
      for (int j = 0; j < 4; ++j)
        acc[i][j] = __builtin_amdgcn_mfma_f32_16x16x32_bf16(a[i], b[j], acc[i][j], 0, 0, 0);
  }

#pragma unroll
  for (int i = 0; i < 4; ++i)
#pragma unroll
    for (int j = 0; j < 4; ++j)
#pragma unroll
      for (int r = 0; r < 4; ++r)
        Out[(size_t)(m0 + i * 16 + quad * 4 + r) * DIMN + n0 + j * 16 + c] = acc[i][j][r];
}

extern "C" void kernel_launch(void* const* d_in, const int* in_sizes, int n_in,
                              void* d_out, int out_size, void* d_ws, size_t ws_size,
                              hipStream_t stream) {
  const float* X = (const float*)d_in[0];
  const float* Wq = (const float*)d_in[1];
  const float* Wk = (const float*)d_in[2];
  const float* Wv = (const float*)d_in[3];
  const float* Wo = (const float*)d_in[4];
  float* Out = (float*)d_out;

  const size_t M1 = (size_t)1 << 20;
  unsigned short* ws16 = (unsigned short*)d_ws;

  if (ws_size >= (size_t)48 * 1024 * 1024) {
    unsigned short* Xb = ws16;            // 4M elems
    unsigned short* Wb = ws16 + 4 * M1;   // 4 x 1M (Wq,Wk,Wv,Wo contiguous)
    unsigned short* Qb = ws16 + 8 * M1;
    unsigned short* Kb = ws16 + 12 * M1;
    unsigned short* VT = ws16 + 16 * M1;
    unsigned short* AO = ws16 + 20 * M1;
    cvt_all<<<4096, 256, 0, stream>>>(X, Wq, Wk, Wv, Wo, ws16);
    gemm_qkv<<<dim3(32, 24), 256, 0, stream>>>(Xb, Wb, Qb, Kb, VT);
    attn4<<<dim3(LL / 128, BB * NH), 256, 0, stream>>>(Qb, Kb, VT, AO);
    gemm_o<<<dim3(32, 16), 256, 0, stream>>>(AO, Wb + 3 * M1, Out);
  } else {
    unsigned short* Qb = ws16;
    unsigned short* Kb = ws16 + 4 * M1;
    unsigned short* VT = ws16 + 8 * M1;
    unsigned short* AO = ws16 + 12 * M1;
    qkv_proj_f<<<dim3(64, 48), 64, 0, stream>>>(X, Wq, Wk, Wv, Qb, Kb, VT);
    attn4<<<dim3(LL / 128, BB * NH), 256, 0, stream>>>(Qb, Kb, VT, AO);
    o_proj_f<<<dim3(64, 16), 64, 0, stream>>>(AO, Wo, Out);
  }
}

// Round 6
// 191.492 us; speedup vs baseline: 2.6613x; 1.0281x over previous
//
#include <hip/hip_runtime.h>

// MultiHeadAttention: out = softmax((XWq^T)(XWk^T)^T / 8) (XWv^T) Wo^T
// B=2, L=2048, DIM=1024, H=16, D=64. fp32 in/out, bf16 MFMA compute.
//
// R6: attn5 computes S^T = K Q^T so the score registers ARE the PV B-operand
//     fragment (P^T) under a fixed key permutation folded into VT's global
//     layout -> P never touches LDS (no ds_writes, no lgkm drain). O
//     accumulated transposed (O^T = V^T P^T). LDS = double-buffered K/V
//     (64 KB), one barrier per 128-key tile, staging overlaps compute.

#define DIMN 1024
#define NH 16
#define HD 64
#define BB 2
#define LL 2048

typedef float f32x4 __attribute__((ext_vector_type(4)));
typedef short s16x8 __attribute__((ext_vector_type(8)));

#define QSCALE 0.18033688011112042f  // log2(e)/8, folds softmax exp2 domain

static __device__ __forceinline__ unsigned short f2bf(float f) {
  unsigned u = __float_as_uint(f);
  u += 0x7fffu + ((u >> 16) & 1u);   // RNE
  return (unsigned short)(u >> 16);
}
static __device__ __forceinline__ unsigned packbf2(float lo, float hi) {
  return (unsigned)f2bf(lo) | ((unsigned)f2bf(hi) << 16);
}
static __device__ __forceinline__ float xexp2(float x) {
#if __has_builtin(__builtin_amdgcn_exp2f)
  return __builtin_amdgcn_exp2f(x);
#else
  return exp2f(x);
#endif
}
static __device__ __forceinline__ s16x8 cvt8(float4 a, float4 b) {
  s16x8 r;
  r[0] = (short)f2bf(a.x); r[1] = (short)f2bf(a.y);
  r[2] = (short)f2bf(a.z); r[3] = (short)f2bf(a.w);
  r[4] = (short)f2bf(b.x); r[5] = (short)f2bf(b.y);
  r[6] = (short)f2bf(b.z); r[7] = (short)f2bf(b.w);
  return r;
}
// async global->LDS, 16B/lane; LDS dest is wave-uniform base + lane*16
static __device__ __forceinline__ void gld16(const unsigned short* g,
                                             unsigned short* l) {
#if __has_builtin(__builtin_amdgcn_global_load_lds)
  __builtin_amdgcn_global_load_lds(
      (const __attribute__((address_space(1))) void*)g,
      (__attribute__((address_space(3))) void*)l, 16, 0, 0);
#else
  ((uint4*)l)[threadIdx.x & 63] = ((const uint4*)g)[0];
#endif
}

// V storage permutation within each 128-seq group: position holding phys seq s:
// pos = b6*64 + b5*32 + (bits3:2)*8 + bit4*4 + bits1:0   (bits of s)
static __device__ __forceinline__ int vpos(int s128) {
  return (s128 & 0x60) | ((s128 & 0x0C) << 1) | ((s128 & 0x10) >> 2) | (s128 & 3);
}

// ---------------- fp32 -> bf16 pre-convert (X + 4 weights) ----------------
__global__ __launch_bounds__(256) void cvt_all(
    const float* __restrict__ X, const float* __restrict__ Wq,
    const float* __restrict__ Wk, const float* __restrict__ Wv,
    const float* __restrict__ Wo, unsigned short* __restrict__ out) {
  const int blk = blockIdx.x;
  const float* src;
  unsigned short* dst;
  size_t off;
  if (blk < 2048) {
    src = X; dst = out; off = (size_t)blk * 2048;
  } else {
    int s = (blk - 2048) >> 9;
    src = (s == 0) ? Wq : (s == 1) ? Wk : (s == 2) ? Wv : Wo;
    dst = out + ((size_t)1 << 22) + (size_t)s * (1u << 20);
    off = (size_t)((blk - 2048) & 511) * 2048;
  }
  size_t i = off + (size_t)threadIdx.x * 8;
  float4 v0 = *(const float4*)(src + i);
  float4 v1 = *(const float4*)(src + i + 4);
  uint4 o;
  o.x = packbf2(v0.x, v0.y); o.y = packbf2(v0.z, v0.w);
  o.z = packbf2(v1.x, v1.y); o.w = packbf2(v1.z, v1.w);
  *(uint4*)(dst + i) = o;
}

// ---------------- fused QKV projection, 128x128 LDS-staged ----------------
__global__ __launch_bounds__(256) void gemm_qkv(
    const unsigned short* __restrict__ Xb, const unsigned short* __restrict__ Wb,
    unsigned short* __restrict__ Qb, unsigned short* __restrict__ Kb,
    unsigned short* __restrict__ VT) {
  __shared__ __align__(16) unsigned short Al[128 * 32];
  __shared__ __align__(16) unsigned short Bl[128 * 32];
  const int m0 = blockIdx.x * 128;
  const int n0g = blockIdx.y * 128;
  const int sel = n0g >> 10;
  const int tid = threadIdx.x;
  const int w = tid >> 6, lane = tid & 63;
  const int c = lane & 15, quad = lane >> 4;
  const int wm = (w & 1) * 64, wn = (w >> 1) * 64;

  f32x4 zero = {0.f, 0.f, 0.f, 0.f};
  f32x4 acc[4][4];
#pragma unroll
  for (int i = 0; i < 4; ++i)
#pragma unroll
    for (int j = 0; j < 4; ++j) acc[i][j] = zero;

  const int srow = w * 32 + (lane >> 2);
  const int scol = (lane & 3) * 8;
  const unsigned short* gA = Xb + (size_t)(m0 + srow) * DIMN + scol;
  const unsigned short* gB = Wb + (size_t)(n0g + srow) * DIMN + scol;
  unsigned short* lA0 = Al + (w * 32) * 32;
  unsigned short* lA1 = Al + (w * 32 + 16) * 32;
  unsigned short* lB0 = Bl + (w * 32) * 32;
  unsigned short* lB1 = Bl + (w * 32 + 16) * 32;

  for (int k0 = 0; k0 < DIMN; k0 += 32) {
    __syncthreads();
    gld16(gA + k0, lA0);
    gld16(gA + k0 + 16 * DIMN, lA1);
    gld16(gB + k0, lB0);
    gld16(gB + k0 + 16 * DIMN, lB1);
    __syncthreads();
    s16x8 a[4], b[4];
#pragma unroll
    for (int i = 0; i < 4; ++i)
      a[i] = *(const s16x8*)&Al[(wm + i * 16 + c) * 32 + quad * 8];
#pragma unroll
    for (int j = 0; j < 4; ++j)
      b[j] = *(const s16x8*)&Bl[(wn + j * 16 + c) * 32 + quad * 8];
    if (sel != 2) {
#pragma unroll
      for (int i = 0; i < 4; ++i)
#pragma unroll
        for (int j = 0; j < 4; ++j)
          acc[i][j] = __builtin_amdgcn_mfma_f32_16x16x32_bf16(a[i], b[j], acc[i][j], 0, 0, 0);
    } else {
#pragma unroll
      for (int i = 0; i < 4; ++i)
#pragma unroll
        for (int j = 0; j < 4; ++j)  // swapped -> C^T in regs
          acc[i][j] = __builtin_amdgcn_mfma_f32_16x16x32_bf16(b[j], a[i], acc[i][j], 0, 0, 0);
    }
  }

  const int n0 = n0g & 1023;
  if (sel != 2) {
    unsigned short* Out = (sel == 0) ? Qb : Kb;
    const float scale = (sel == 0) ? QSCALE : 1.0f;
#pragma unroll
    for (int i = 0; i < 4; ++i)
#pragma unroll
      for (int j = 0; j < 4; ++j)
#pragma unroll
        for (int r = 0; r < 4; ++r) {
          int row = m0 + wm + i * 16 + quad * 4 + r;
          int col = n0 + wn + j * 16 + c;
          Out[(((size_t)(row >> 11) * NH + (col >> 6)) * LL + (row & 2047)) * HD + (col & 63)] =
              f2bf(acc[i][j][r] * scale);
        }
  } else {
    // V^T stored [B,H,D,L]; seq index permuted per 128-group via vpos()
#pragma unroll
    for (int i = 0; i < 4; ++i) {
      const int pos = vpos(wm + i * 16 + 2 * 0 + 0);  // base; c folded below
#pragma unroll
      for (int j = 0; j < 4; ++j)
#pragma unroll
        for (int r = 0; r < 4; ++r) {
          int n = n0 + wn + j * 16 + quad * 4 + r;    // d/h index
          int sp = vpos(wm + i * 16 + c);             // storage pos in group
          int m = m0 + sp;
          int bi = (m0 + wm) >> 11;
          VT[(((size_t)bi * NH + (n >> 6)) * HD + (n & 63)) * LL + (m & 2047)] =
              f2bf(acc[i][j][r]);
        }
      (void)pos;
    }
  }
}

// ---------------- output projection, 128x64 LDS-staged ----------------
__global__ __launch_bounds__(256) void gemm_o(
    const unsigned short* __restrict__ A, const unsigned short* __restrict__ Wob,
    float* __restrict__ Out) {
  __shared__ __align__(16) unsigned short Al[128 * 32];
  __shared__ __align__(16) unsigned short Bl[64 * 32];
  const int m0 = blockIdx.x * 128;
  const int n0 = blockIdx.y * 64;
  const int tid = threadIdx.x;
  const int w = tid >> 6, lane = tid & 63;
  const int c = lane & 15, quad = lane >> 4;
  const int wm = (w & 1) * 64, wn = (w >> 1) * 32;

  f32x4 zero = {0.f, 0.f, 0.f, 0.f};
  f32x4 acc[4][2];
#pragma unroll
  for (int i = 0; i < 4; ++i)
#pragma unroll
    for (int j = 0; j < 2; ++j) acc[i][j] = zero;

  const int srow = w * 32 + (lane >> 2);
  const int brow = w * 16 + (lane >> 2);
  const int scol = (lane & 3) * 8;
  const unsigned short* gA = A + (size_t)(m0 + srow) * DIMN + scol;
  const unsigned short* gB = Wob + (size_t)(n0 + brow) * DIMN + scol;
  unsigned short* lA0 = Al + (w * 32) * 32;
  unsigned short* lA1 = Al + (w * 32 + 16) * 32;
  unsigned short* lB0 = Bl + (w * 16) * 32;

  for (int k0 = 0; k0 < DIMN; k0 += 32) {
    __syncthreads();
    gld16(gA + k0, lA0);
    gld16(gA + k0 + 16 * DIMN, lA1);
    gld16(gB + k0, lB0);
    __syncthreads();
    s16x8 a[4], b[2];
#pragma unroll
    for (int i = 0; i < 4; ++i)
      a[i] = *(const s16x8*)&Al[(wm + i * 16 + c) * 32 + quad * 8];
#pragma unroll
    for (int j = 0; j < 2; ++j)
      b[j] = *(const s16x8*)&Bl[(wn + j * 16 + c) * 32 + quad * 8];
#pragma unroll
    for (int i = 0; i < 4; ++i)
#pragma unroll
      for (int j = 0; j < 2; ++j)
        acc[i][j] = __builtin_amdgcn_mfma_f32_16x16x32_bf16(a[i], b[j], acc[i][j], 0, 0, 0);
  }

#pragma unroll
  for (int i = 0; i < 4; ++i)
#pragma unroll
    for (int j = 0; j < 2; ++j)
#pragma unroll
      for (int r = 0; r < 4; ++r)
        Out[(size_t)(m0 + wm + i * 16 + quad * 4 + r) * DIMN + n0 + wn + j * 16 + c] =
            acc[i][j][r];
}

// ---------------- flash attention, register-resident P ----------------
// grid (16, B*NH), block 256 (4 waves x 32 q-rows). S^T = K Q^T keeps scores
// in the PV B-operand layout (P^T); O^T = V^T P^T. K/V double-buffered via
// gld16 into XOR-swizzled tiles; one barrier per 128-key tile.
__global__ __launch_bounds__(256) void attn5(
    const unsigned short* __restrict__ Qb, const unsigned short* __restrict__ Kb,
    const unsigned short* __restrict__ VT, unsigned short* __restrict__ AO) {
  __shared__ __align__(16) unsigned short Kl[2 * 128 * 64];   // 32 KB
  __shared__ __align__(16) unsigned short Vtl[2 * 64 * 128];  // 32 KB

  const int bh = blockIdx.y;
  const int tid = threadIdx.x;
  const int w = tid >> 6, lane = tid & 63;
  const int c = lane & 15, quad = lane >> 4;
  const int q0 = blockIdx.x * 128 + w * 32;

  const unsigned short* Qh = Qb + (size_t)bh * LL * HD;
  const unsigned short* Kh = Kb + (size_t)bh * LL * HD;
  const unsigned short* Vh = VT + (size_t)bh * HD * LL;   // [d][l], permuted

  // Q fragments (B-operand): lane c holds q-row q0+m*16+c
  s16x8 qf[2][2];
#pragma unroll
  for (int m = 0; m < 2; ++m)
#pragma unroll
    for (int f = 0; f < 2; ++f)
      qf[m][f] = *(const s16x8*)(Qh + (size_t)(q0 + m * 16 + c) * HD + f * 32 + quad * 8);

  f32x4 zero = {0.f, 0.f, 0.f, 0.f};
  f32x4 o[2][4];     // O^T accumulators: row=d_local, col=q
  float lsum[2] = {0.f, 0.f};
#pragma unroll
  for (int m = 0; m < 2; ++m)
#pragma unroll
    for (int dc = 0; dc < 4; ++dc) o[m][dc] = zero;

  // staging geometry (loop-invariant)
  const int l8 = lane >> 3, p8 = lane & 7;
  const unsigned short* gK = Kh + (size_t)(w * 8 + l8) * HD + ((p8 ^ l8) * 8);
  const int l16 = lane >> 4, p16 = lane & 15;
  const int vrow = w * 4 + l16;
  const unsigned short* gV = Vh + (size_t)vrow * LL + ((p16 ^ vrow) * 8);

  // compute-side K chunk offsets (swizzle: phys = logical ^ (row&7))
  const int kpa = (quad ^ (c & 7)) * 8;
  const int kpb = ((quad + 4) ^ (c & 7)) * 8;

#define STAGE(buf, k0)                                                        \
  do {                                                                        \
    unsigned short* lK_ = Kl + (buf) * (128 * 64) + (w * 8) * 64;             \
    unsigned short* lV_ = Vtl + (buf) * (64 * 128) + (w * 4) * 128;           \
    _Pragma("unroll")                                                         \
    for (int s_ = 0; s_ < 4; ++s_)                                            \
      gld16(gK + (size_t)((k0) + s_ * 32) * HD, lK_ + s_ * 32 * 64);          \
    _Pragma("unroll")                                                         \
    for (int s_ = 0; s_ < 4; ++s_)                                            \
      gld16(gV + (size_t)(s_ * 16) * LL + (k0), lV_ + s_ * 16 * 128);         \
  } while (0)

  STAGE(0, 0);

  for (int it = 0; it < LL / 128; ++it) {
    __syncthreads();   // drains stage of buffer it&1
    if (it + 1 < LL / 128) STAGE((it + 1) & 1, (it + 1) * 128);
    const unsigned short* Kt = Kl + (it & 1) * (128 * 64);
    const unsigned short* Vt = Vtl + (it & 1) * (64 * 128);

#pragma unroll
    for (int g = 0; g < 2; ++g) {
      // S^T = K Q^T: lane c holds scores for q=m*16+c, keys t*16+quad*4+r
      f32x4 s[2][4];
#pragma unroll
      for (int t4 = 0; t4 < 4; ++t4) {
        const unsigned short* kr = Kt + ((g * 4 + t4) * 16 + c) * 64;
        s16x8 kfa = *(const s16x8*)(kr + kpa);
        s16x8 kfb = *(const s16x8*)(kr + kpb);
#pragma unroll
        for (int m = 0; m < 2; ++m) {
          s[m][t4] = __builtin_amdgcn_mfma_f32_16x16x32_bf16(kfa, qf[m][0], zero, 0, 0, 0);
          s[m][t4] = __builtin_amdgcn_mfma_f32_16x16x32_bf16(kfb, qf[m][1], s[m][t4], 0, 0, 0);
        }
      }
      // p = exp2(s) in place; accumulate per-lane l partial
      float p[2][4][4];
#pragma unroll
      for (int m = 0; m < 2; ++m) {
        float acc_l = 0.f;
#pragma unroll
        for (int t4 = 0; t4 < 4; ++t4)
#pragma unroll
          for (int r = 0; r < 4; ++r) {
            float e = xexp2(s[m][t4][r]);
            p[m][t4][r] = e;
            acc_l += e;
          }
        lsum[m] += acc_l;
      }
      // O^T += V^T P^T : P^T B-frags built in-register (RTZ bf16 pack)
#pragma unroll
      for (int kh = 0; kh < 2; ++kh) {
        const int kk = g * 2 + kh;
        s16x8 pf[2];
#pragma unroll
        for (int m = 0; m < 2; ++m) {
          unsigned u0 = __builtin_amdgcn_perm(__float_as_uint(p[m][2 * kh][1]),
                                              __float_as_uint(p[m][2 * kh][0]), 0x07060302u);
          unsigned u1 = __builtin_amdgcn_perm(__float_as_uint(p[m][2 * kh][3]),
                                              __float_as_uint(p[m][2 * kh][2]), 0x07060302u);
          unsigned u2 = __builtin_amdgcn_perm(__float_as_uint(p[m][2 * kh + 1][1]),
                                              __float_as_uint(p[m][2 * kh + 1][0]), 0x07060302u);
          unsigned u3 = __builtin_amdgcn_perm(__float_as_uint(p[m][2 * kh + 1][3]),
                                              __float_as_uint(p[m][2 * kh + 1][2]), 0x07060302u);
          unsigned pu[4] = {u0, u1, u2, u3};
          pf[m] = *(const s16x8*)pu;
        }
#pragma unroll
        for (int dc = 0; dc < 4; ++dc) {
          s16x8 vf = *(const s16x8*)(Vt + (dc * 16 + c) * 128 + (((kk * 4 + quad) ^ c) * 8));
          o[0][dc] = __builtin_amdgcn_mfma_f32_16x16x32_bf16(vf, pf[0], o[0][dc], 0, 0, 0);
          o[1][dc] = __builtin_amdgcn_mfma_f32_16x16x32_bf16(vf, pf[1], o[1][dc], 0, 0, 0);
        }
      }
    }
  }
#undef STAGE

  // epilogue: l = sum over quads; normalize; write AO [B,L,DIM] (8B stores)
  const int bi = bh >> 4, h = bh & 15;
#pragma unroll
  for (int m = 0; m < 2; ++m) {
    float l = lsum[m];
    l += __shfl_xor(l, 16);
    l += __shfl_xor(l, 32);
    float inv = 1.0f / l;
    unsigned short* dst = AO + ((size_t)bi * LL + q0 + m * 16 + c) * DIMN + h * HD + quad * 4;
#pragma unroll
    for (int dc = 0; dc < 4; ++dc) {
      uint2 st;
      st.x = packbf2(o[m][dc][0] * inv, o[m][dc][1] * inv);
      st.y = packbf2(o[m][dc][2] * inv, o[m][dc][3] * inv);
      *(uint2*)(dst + dc * 16) = st;
    }
  }
}

// ---------------- fp32 fallback path (1-wave GEMMs), ws < 48 MiB ----------------
__global__ __launch_bounds__(64) void qkv_proj_f(
    const float* __restrict__ X, const float* __restrict__ Wq,
    const float* __restrict__ Wk, const float* __restrict__ Wv,
    unsigned short* __restrict__ Qb, unsigned short* __restrict__ Kb,
    unsigned short* __restrict__ VT) {
  const int m0 = blockIdx.x * 64;
  const int n0g = blockIdx.y * 64;
  const int sel = n0g >> 10;
  const int n0 = n0g & 1023;
  const float* W = (sel == 0) ? Wq : (sel == 1) ? Wk : Wv;
  const int lane = threadIdx.x;
  const int c = lane & 15, quad = lane >> 4;

  f32x4 zero = {0.f, 0.f, 0.f, 0.f};
  f32x4 acc[4][4];
#pragma unroll
  for (int i = 0; i < 4; ++i)
#pragma unroll
    for (int j = 0; j < 4; ++j) acc[i][j] = zero;

  const float* ab = X + (size_t)(m0 + c) * DIMN + quad * 8;
  const float* bb = W + (size_t)(n0 + c) * DIMN + quad * 8;

  for (int k0 = 0; k0 < DIMN; k0 += 32) {
    s16x8 a[4], b[4];
#pragma unroll
    for (int i = 0; i < 4; ++i) {
      const float* pp = ab + i * 16 * DIMN + k0;
      a[i] = cvt8(*(const float4*)pp, *(const float4*)(pp + 4));
    }
#pragma unroll
    for (int j = 0; j < 4; ++j) {
      const float* pp = bb + j * 16 * DIMN + k0;
      b[j] = cvt8(*(const float4*)pp, *(const float4*)(pp + 4));
    }
    if (sel != 2) {
#pragma unroll
      for (int i = 0; i < 4; ++i)
#pragma unroll
        for (int j = 0; j < 4; ++j)
          acc[i][j] = __builtin_amdgcn_mfma_f32_16x16x32_bf16(a[i], b[j], acc[i][j], 0, 0, 0);
    } else {
#pragma unroll
      for (int i = 0; i < 4; ++i)
#pragma unroll
        for (int j = 0; j < 4; ++j)
          acc[i][j] = __builtin_amdgcn_mfma_f32_16x16x32_bf16(b[j], a[i], acc[i][j], 0, 0, 0);
    }
  }

  if (sel != 2) {
    unsigned short* Out = (sel == 0) ? Qb : Kb;
    const float scale = (sel == 0) ? QSCALE : 1.0f;
#pragma unroll
    for (int i = 0; i < 4; ++i)
#pragma unroll
      for (int j = 0; j < 4; ++j)
#pragma unroll
        for (int r = 0; r < 4; ++r) {
          int row = m0 + i * 16 + quad * 4 + r;
          int nl = n0 + j * 16 + c;
          int bi = row >> 11, li = row & 2047;
          int h = nl >> 6, d = nl & 63;
          Out[(((size_t)bi * NH + h) * LL + li) * HD + d] = f2bf(acc[i][j][r] * scale);
        }
  } else {
#pragma unroll
    for (int i = 0; i < 4; ++i) {
#pragma unroll
      for (int j = 0; j < 4; ++j)
#pragma unroll
        for (int r = 0; r < 4; ++r) {
          int n = n0 + j * 16 + quad * 4 + r;
          int s128 = (m0 & 64) + i * 16 + c;
          int m = (m0 & ~127) + vpos(s128);
          int h = n >> 6, d = n & 63;
          int bi = m0 >> 11;
          VT[(((size_t)bi * NH + h) * HD + d) * LL + (m & 2047)] = f2bf(acc[i][j][r]);
        }
    }
  }
}

__global__ __launch_bounds__(64) void o_proj_f(
    const unsigned short* __restrict__ A, const float* __restrict__ Wo,
    float* __restrict__ Out) {
  const int m0 = blockIdx.x * 64, n0 = blockIdx.y * 64;
  const int lane = threadIdx.x;
  const int c = lane & 15, quad = lane >> 4;

  f32x4 zero = {0.f, 0.f, 0.f, 0.f};
  f32x4 acc[4][4];
#pragma unroll
  for (int i = 0; i < 4; ++i)
#pragma unroll
    for (int j = 0; j < 4; ++j) acc[i][j] = zero;

  const unsigned short* ab = A + (size_t)(m0 + c) * DIMN + quad * 8;
  const float* bb = Wo + (size_t)(n0 + c) * DIMN + quad * 8;

  for (int k0 = 0; k0 < DIMN; k0 += 32) {
    s16x8 a[4], b[4];
#pragma unroll
    for (int i = 0; i < 4; ++i) a[i] = *(const s16x8*)(ab + i * 16 * DIMN + k0);
#pragma unroll
    for (int j = 0; j < 4; ++j) {
      const float* pp = bb + j * 16 * DIMN + k0;
      b[j] = cvt8(*(const float4*)pp, *(const float4*)(pp + 4));
    }
#pragma unroll
    for (int i = 0; i < 4; ++i)
#pragma unroll
      for (int j = 0; j < 4; ++j)
        acc[i][j] = __builtin_amdgcn_mfma_f32_16x16x32_bf16(a[i], b[j], acc[i][j], 0, 0, 0);
  }

#pragma unroll
  for (int i = 0; i < 4; ++i)
#pragma unroll
    for (int j = 0; j < 4; ++j)
#pragma unroll
      for (int r = 0; r < 4; ++r)
        Out[(size_t)(m0 + i * 16 + quad * 4 + r) * DIMN + n0 + j * 16 + c] = acc[i][j][r];
}

extern "C" void kernel_launch(void* const* d_in, const int* in_sizes, int n_in,
                              void* d_out, int out_size, void* d_ws, size_t ws_size,
                              hipStream_t stream) {
  const float* X = (const float*)d_in[0];
  const float* Wq = (const float*)d_in[1];
  const float* Wk = (const float*)d_in[2];
  const float* Wv = (const float*)d_in[3];
  const float* Wo = (const float*)d_in[4];
  float* Out = (float*)d_out;

  const size_t M1 = (size_t)1 << 20;
  unsigned short* ws16 = (unsigned short*)d_ws;

  if (ws_size >= (size_t)48 * 1024 * 1024) {
    unsigned short* Xb = ws16;            // 4M elems
    unsigned short* Wb = ws16 + 4 * M1;   // 4 x 1M (Wq,Wk,Wv,Wo contiguous)
    unsigned short* Qb = ws16 + 8 * M1;
    unsigned short* Kb = ws16 + 12 * M1;
    unsigned short* VT = ws16 + 16 * M1;
    unsigned short* AO = ws16 + 20 * M1;
    cvt_all<<<4096, 256, 0, stream>>>(X, Wq, Wk, Wv, Wo, ws16);
    gemm_qkv<<<dim3(32, 24), 256, 0, stream>>>(Xb, Wb, Qb, Kb, VT);
    attn5<<<dim3(LL / 128, BB * NH), 256, 0, stream>>>(Qb, Kb, VT, AO);
    gemm_o<<<dim3(32, 16), 256, 0, stream>>>(AO, Wb + 3 * M1, Out);
  } else {
    unsigned short* Qb = ws16;
    unsigned short* Kb = ws16 + 4 * M1;
    unsigned short* VT = ws16 + 8 * M1;
    unsigned short* AO = ws16 + 12 * M1;
    qkv_proj_f<<<dim3(64, 48), 64, 0, stream>>>(X, Wq, Wk, Wv, Qb, Kb, VT);
    attn5<<<dim3(LL / 128, BB * NH), 256, 0, stream>>>(Qb, Kb, VT, AO);
    o_proj_f<<<dim3(64, 16), 64, 0, stream>>>(AO, Wo, Out);
  }
}

// Round 7
// 187.234 us; speedup vs baseline: 2.7218x; 1.0227x over previous
//
#include <hip/hip_runtime.h>

// MultiHeadAttention: out = softmax((XWq^T)(XWk^T)^T / 8) (XWv^T) Wo^T
// B=2, L=2048, DIM=1024, H=16, D=64. fp32 in/out, bf16 MFMA compute.
//
// R7: attn6 = 8 waves x 16 q-rows (512-thread block) on the same 128-row /
//     128-key double-buffered structure -> 4 waves/SIMD (was 2) to hide the
//     QK->exp2->pack->PV dependency chain. Algorithm & layouts unchanged.

#define DIMN 1024
#define NH 16
#define HD 64
#define BB 2
#define LL 2048

typedef float f32x4 __attribute__((ext_vector_type(4)));
typedef short s16x8 __attribute__((ext_vector_type(8)));

#define QSCALE 0.18033688011112042f  // log2(e)/8, folds softmax exp2 domain

static __device__ __forceinline__ unsigned short f2bf(float f) {
  unsigned u = __float_as_uint(f);
  u += 0x7fffu + ((u >> 16) & 1u);   // RNE
  return (unsigned short)(u >> 16);
}
static __device__ __forceinline__ unsigned packbf2(float lo, float hi) {
  return (unsigned)f2bf(lo) | ((unsigned)f2bf(hi) << 16);
}
static __device__ __forceinline__ float xexp2(float x) {
#if __has_builtin(__builtin_amdgcn_exp2f)
  return __builtin_amdgcn_exp2f(x);
#else
  return exp2f(x);
#endif
}
static __device__ __forceinline__ s16x8 cvt8(float4 a, float4 b) {
  s16x8 r;
  r[0] = (short)f2bf(a.x); r[1] = (short)f2bf(a.y);
  r[2] = (short)f2bf(a.z); r[3] = (short)f2bf(a.w);
  r[4] = (short)f2bf(b.x); r[5] = (short)f2bf(b.y);
  r[6] = (short)f2bf(b.z); r[7] = (short)f2bf(b.w);
  return r;
}
// async global->LDS, 16B/lane; LDS dest is wave-uniform base + lane*16
static __device__ __forceinline__ void gld16(const unsigned short* g,
                                             unsigned short* l) {
#if __has_builtin(__builtin_amdgcn_global_load_lds)
  __builtin_amdgcn_global_load_lds(
      (const __attribute__((address_space(1))) void*)g,
      (__attribute__((address_space(3))) void*)l, 16, 0, 0);
#else
  ((uint4*)l)[threadIdx.x & 63] = ((const uint4*)g)[0];
#endif
}

// V storage permutation within each 128-seq group: position holding phys seq s:
// pos = b6*64 + b5*32 + (bits3:2)*8 + bit4*4 + bits1:0   (bits of s)
static __device__ __forceinline__ int vpos(int s128) {
  return (s128 & 0x60) | ((s128 & 0x0C) << 1) | ((s128 & 0x10) >> 2) | (s128 & 3);
}

// ---------------- fp32 -> bf16 pre-convert (X + 4 weights) ----------------
__global__ __launch_bounds__(256) void cvt_all(
    const float* __restrict__ X, const float* __restrict__ Wq,
    const float* __restrict__ Wk, const float* __restrict__ Wv,
    const float* __restrict__ Wo, unsigned short* __restrict__ out) {
  const int blk = blockIdx.x;
  const float* src;
  unsigned short* dst;
  size_t off;
  if (blk < 2048) {
    src = X; dst = out; off = (size_t)blk * 2048;
  } else {
    int s = (blk - 2048) >> 9;
    src = (s == 0) ? Wq : (s == 1) ? Wk : (s == 2) ? Wv : Wo;
    dst = out + ((size_t)1 << 22) + (size_t)s * (1u << 20);
    off = (size_t)((blk - 2048) & 511) * 2048;
  }
  size_t i = off + (size_t)threadIdx.x * 8;
  float4 v0 = *(const float4*)(src + i);
  float4 v1 = *(const float4*)(src + i + 4);
  uint4 o;
  o.x = packbf2(v0.x, v0.y); o.y = packbf2(v0.z, v0.w);
  o.z = packbf2(v1.x, v1.y); o.w = packbf2(v1.z, v1.w);
  *(uint4*)(dst + i) = o;
}

// ---------------- fused QKV projection, 128x128 LDS-staged ----------------
__global__ __launch_bounds__(256) void gemm_qkv(
    const unsigned short* __restrict__ Xb, const unsigned short* __restrict__ Wb,
    unsigned short* __restrict__ Qb, unsigned short* __restrict__ Kb,
    unsigned short* __restrict__ VT) {
  __shared__ __align__(16) unsigned short Al[128 * 32];
  __shared__ __align__(16) unsigned short Bl[128 * 32];
  const int m0 = blockIdx.x * 128;
  const int n0g = blockIdx.y * 128;
  const int sel = n0g >> 10;
  const int tid = threadIdx.x;
  const int w = tid >> 6, lane = tid & 63;
  const int c = lane & 15, quad = lane >> 4;
  const int wm = (w & 1) * 64, wn = (w >> 1) * 64;

  f32x4 zero = {0.f, 0.f, 0.f, 0.f};
  f32x4 acc[4][4];
#pragma unroll
  for (int i = 0; i < 4; ++i)
#pragma unroll
    for (int j = 0; j < 4; ++j) acc[i][j] = zero;

  const int srow = w * 32 + (lane >> 2);
  const int scol = (lane & 3) * 8;
  const unsigned short* gA = Xb + (size_t)(m0 + srow) * DIMN + scol;
  const unsigned short* gB = Wb + (size_t)(n0g + srow) * DIMN + scol;
  unsigned short* lA0 = Al + (w * 32) * 32;
  unsigned short* lA1 = Al + (w * 32 + 16) * 32;
  unsigned short* lB0 = Bl + (w * 32) * 32;
  unsigned short* lB1 = Bl + (w * 32 + 16) * 32;

  for (int k0 = 0; k0 < DIMN; k0 += 32) {
    __syncthreads();
    gld16(gA + k0, lA0);
    gld16(gA + k0 + 16 * DIMN, lA1);
    gld16(gB + k0, lB0);
    gld16(gB + k0 + 16 * DIMN, lB1);
    __syncthreads();
    s16x8 a[4], b[4];
#pragma unroll
    for (int i = 0; i < 4; ++i)
      a[i] = *(const s16x8*)&Al[(wm + i * 16 + c) * 32 + quad * 8];
#pragma unroll
    for (int j = 0; j < 4; ++j)
      b[j] = *(const s16x8*)&Bl[(wn + j * 16 + c) * 32 + quad * 8];
    if (sel != 2) {
#pragma unroll
      for (int i = 0; i < 4; ++i)
#pragma unroll
        for (int j = 0; j < 4; ++j)
          acc[i][j] = __builtin_amdgcn_mfma_f32_16x16x32_bf16(a[i], b[j], acc[i][j], 0, 0, 0);
    } else {
#pragma unroll
      for (int i = 0; i < 4; ++i)
#pragma unroll
        for (int j = 0; j < 4; ++j)  // swapped -> C^T in regs
          acc[i][j] = __builtin_amdgcn_mfma_f32_16x16x32_bf16(b[j], a[i], acc[i][j], 0, 0, 0);
    }
  }

  const int n0 = n0g & 1023;
  if (sel != 2) {
    unsigned short* Out = (sel == 0) ? Qb : Kb;
    const float scale = (sel == 0) ? QSCALE : 1.0f;
#pragma unroll
    for (int i = 0; i < 4; ++i)
#pragma unroll
      for (int j = 0; j < 4; ++j)
#pragma unroll
        for (int r = 0; r < 4; ++r) {
          int row = m0 + wm + i * 16 + quad * 4 + r;
          int col = n0 + wn + j * 16 + c;
          Out[(((size_t)(row >> 11) * NH + (col >> 6)) * LL + (row & 2047)) * HD + (col & 63)] =
              f2bf(acc[i][j][r] * scale);
        }
  } else {
    // V^T stored [B,H,D,L]; seq index permuted per 128-group via vpos()
#pragma unroll
    for (int i = 0; i < 4; ++i) {
#pragma unroll
      for (int j = 0; j < 4; ++j)
#pragma unroll
        for (int r = 0; r < 4; ++r) {
          int n = n0 + wn + j * 16 + quad * 4 + r;    // d/h index
          int sp = vpos(wm + i * 16 + c);             // storage pos in group
          int m = m0 + sp;
          int bi = (m0 + wm) >> 11;
          VT[(((size_t)bi * NH + (n >> 6)) * HD + (n & 63)) * LL + (m & 2047)] =
              f2bf(acc[i][j][r]);
        }
    }
  }
}

// ---------------- output projection, 128x64 LDS-staged ----------------
__global__ __launch_bounds__(256) void gemm_o(
    const unsigned short* __restrict__ A, const unsigned short* __restrict__ Wob,
    float* __restrict__ Out) {
  __shared__ __align__(16) unsigned short Al[128 * 32];
  __shared__ __align__(16) unsigned short Bl[64 * 32];
  const int m0 = blockIdx.x * 128;
  const int n0 = blockIdx.y * 64;
  const int tid = threadIdx.x;
  const int w = tid >> 6, lane = tid & 63;
  const int c = lane & 15, quad = lane >> 4;
  const int wm = (w & 1) * 64, wn = (w >> 1) * 32;

  f32x4 zero = {0.f, 0.f, 0.f, 0.f};
  f32x4 acc[4][2];
#pragma unroll
  for (int i = 0; i < 4; ++i)
#pragma unroll
    for (int j = 0; j < 2; ++j) acc[i][j] = zero;

  const int srow = w * 32 + (lane >> 2);
  const int brow = w * 16 + (lane >> 2);
  const int scol = (lane & 3) * 8;
  const unsigned short* gA = A + (size_t)(m0 + srow) * DIMN + scol;
  const unsigned short* gB = Wob + (size_t)(n0 + brow) * DIMN + scol;
  unsigned short* lA0 = Al + (w * 32) * 32;
  unsigned short* lA1 = Al + (w * 32 + 16) * 32;
  unsigned short* lB0 = Bl + (w * 16) * 32;

  for (int k0 = 0; k0 < DIMN; k0 += 32) {
    __syncthreads();
    gld16(gA + k0, lA0);
    gld16(gA + k0 + 16 * DIMN, lA1);
    gld16(gB + k0, lB0);
    __syncthreads();
    s16x8 a[4], b[2];
#pragma unroll
    for (int i = 0; i < 4; ++i)
      a[i] = *(const s16x8*)&Al[(wm + i * 16 + c) * 32 + quad * 8];
#pragma unroll
    for (int j = 0; j < 2; ++j)
      b[j] = *(const s16x8*)&Bl[(wn + j * 16 + c) * 32 + quad * 8];
#pragma unroll
    for (int i = 0; i < 4; ++i)
#pragma unroll
      for (int j = 0; j < 2; ++j)
        acc[i][j] = __builtin_amdgcn_mfma_f32_16x16x32_bf16(a[i], b[j], acc[i][j], 0, 0, 0);
  }

#pragma unroll
  for (int i = 0; i < 4; ++i)
#pragma unroll
    for (int j = 0; j < 2; ++j)
#pragma unroll
      for (int r = 0; r < 4; ++r)
        Out[(size_t)(m0 + wm + i * 16 + quad * 4 + r) * DIMN + n0 + wn + j * 16 + c] =
            acc[i][j][r];
}

// ---------------- flash attention, 8 waves x 16 q-rows ----------------
// grid (16, B*NH), block 512. S^T = K Q^T (P^T stays in registers);
// O^T = V^T P^T. K/V double-buffered via gld16 into XOR-swizzled tiles.
__global__ __launch_bounds__(512) void attn6(
    const unsigned short* __restrict__ Qb, const unsigned short* __restrict__ Kb,
    const unsigned short* __restrict__ VT, unsigned short* __restrict__ AO) {
  __shared__ __align__(16) unsigned short Kl[2 * 128 * 64];   // 32 KB
  __shared__ __align__(16) unsigned short Vtl[2 * 64 * 128];  // 32 KB

  const int bh = blockIdx.y;
  const int tid = threadIdx.x;
  const int w = tid >> 6, lane = tid & 63;
  const int c = lane & 15, quad = lane >> 4;
  const int q0 = blockIdx.x * 128 + w * 16;

  const unsigned short* Qh = Qb + (size_t)bh * LL * HD;
  const unsigned short* Kh = Kb + (size_t)bh * LL * HD;
  const unsigned short* Vh = VT + (size_t)bh * HD * LL;   // [d][l], permuted

  // Q fragments (B-operand): lane c holds q-row q0+c
  s16x8 qf0 = *(const s16x8*)(Qh + (size_t)(q0 + c) * HD + quad * 8);
  s16x8 qf1 = *(const s16x8*)(Qh + (size_t)(q0 + c) * HD + 32 + quad * 8);

  f32x4 zero = {0.f, 0.f, 0.f, 0.f};
  f32x4 o[4];     // O^T accumulators: row=d_local, col=q
  float lsum = 0.f;
#pragma unroll
  for (int dc = 0; dc < 4; ++dc) o[dc] = zero;

  // staging geometry (loop-invariant). Wave w stages K rows [w*16,w*16+16),
  // V d-rows [w*8, w*8+8), in two gld16 each.
  const int l8 = lane >> 3, p8 = lane & 7;
  const unsigned short* gK = Kh + (size_t)(w * 16 + l8) * HD + ((p8 ^ l8) * 8);
  const int l16 = lane >> 4, p16 = lane & 15;
  const int vr0 = w * 8 + l16;          // first V row; swizzle key = row & 15
  const int vr1 = w * 8 + 4 + l16;
  const unsigned short* gV0 = Vh + (size_t)vr0 * LL + ((p16 ^ (vr0 & 15)) * 8);
  const unsigned short* gV1 = Vh + (size_t)vr1 * LL + ((p16 ^ (vr1 & 15)) * 8);

  // compute-side K chunk offsets (swizzle: phys = logical ^ (row&7))
  const int kpa = (quad ^ (c & 7)) * 8;
  const int kpb = ((quad + 4) ^ (c & 7)) * 8;

#define STAGE(buf, k0)                                                        \
  do {                                                                        \
    unsigned short* lK_ = Kl + (buf) * (128 * 64) + (w * 16) * 64;            \
    unsigned short* lV_ = Vtl + (buf) * (64 * 128) + (w * 8) * 128;           \
    gld16(gK + (size_t)(k0) * HD, lK_);                                       \
    gld16(gK + (size_t)((k0) + 8) * HD, lK_ + 8 * 64);                        \
    gld16(gV0 + (k0), lV_);                                                   \
    gld16(gV1 + (k0), lV_ + 4 * 128);                                         \
  } while (0)

  STAGE(0, 0);

  for (int it = 0; it < LL / 128; ++it) {
    __syncthreads();   // staged buffer it&1 now visible
    if (it + 1 < LL / 128) STAGE((it + 1) & 1, (it + 1) * 128);
    const unsigned short* Kt = Kl + (it & 1) * (128 * 64);
    const unsigned short* Vt = Vtl + (it & 1) * (64 * 128);

#pragma unroll
    for (int g = 0; g < 2; ++g) {
      // S^T = K Q^T: lane c holds scores for q=q0+c, keys t*16+quad*4+r
      f32x4 s[4];
#pragma unroll
      for (int t4 = 0; t4 < 4; ++t4) {
        const unsigned short* kr = Kt + ((g * 4 + t4) * 16 + c) * 64;
        s16x8 kfa = *(const s16x8*)(kr + kpa);
        s16x8 kfb = *(const s16x8*)(kr + kpb);
        s[t4] = __builtin_amdgcn_mfma_f32_16x16x32_bf16(kfa, qf0, zero, 0, 0, 0);
        s[t4] = __builtin_amdgcn_mfma_f32_16x16x32_bf16(kfb, qf1, s[t4], 0, 0, 0);
      }
      // p = exp2(s); accumulate per-lane l partial
      float p[4][4];
      float acc_l = 0.f;
#pragma unroll
      for (int t4 = 0; t4 < 4; ++t4)
#pragma unroll
        for (int r = 0; r < 4; ++r) {
          float e = xexp2(s[t4][r]);
          p[t4][r] = e;
          acc_l += e;
        }
      lsum += acc_l;
      // O^T += V^T P^T : P^T B-frags built in-register (RTZ bf16 pack)
#pragma unroll
      for (int kh = 0; kh < 2; ++kh) {
        const int kk = g * 2 + kh;
        unsigned pu[4];
        pu[0] = __builtin_amdgcn_perm(__float_as_uint(p[2 * kh][1]),
                                      __float_as_uint(p[2 * kh][0]), 0x07060302u);
        pu[1] = __builtin_amdgcn_perm(__float_as_uint(p[2 * kh][3]),
                                      __float_as_uint(p[2 * kh][2]), 0x07060302u);
        pu[2] = __builtin_amdgcn_perm(__float_as_uint(p[2 * kh + 1][1]),
                                      __float_as_uint(p[2 * kh + 1][0]), 0x07060302u);
        pu[3] = __builtin_amdgcn_perm(__float_as_uint(p[2 * kh + 1][3]),
                                      __float_as_uint(p[2 * kh + 1][2]), 0x07060302u);
        s16x8 pf = *(const s16x8*)pu;
#pragma unroll
        for (int dc = 0; dc < 4; ++dc) {
          s16x8 vf = *(const s16x8*)(Vt + (dc * 16 + c) * 128 + (((kk * 4 + quad) ^ c) * 8));
          o[dc] = __builtin_amdgcn_mfma_f32_16x16x32_bf16(vf, pf, o[dc], 0, 0, 0);
        }
      }
    }
  }
#undef STAGE

  // epilogue: l = sum over quads; normalize; write AO [B,L,DIM] (8B stores)
  const int bi = bh >> 4, h = bh & 15;
  float l = lsum;
  l += __shfl_xor(l, 16);
  l += __shfl_xor(l, 32);
  float inv = 1.0f / l;
  unsigned short* dst = AO + ((size_t)bi * LL + q0 + c) * DIMN + h * HD + quad * 4;
#pragma unroll
  for (int dc = 0; dc < 4; ++dc) {
    uint2 st;
    st.x = packbf2(o[dc][0] * inv, o[dc][1] * inv);
    st.y = packbf2(o[dc][2] * inv, o[dc][3] * inv);
    *(uint2*)(dst + dc * 16) = st;
  }
}

// ---------------- fp32 fallback path (1-wave GEMMs), ws < 48 MiB ----------------
__global__ __launch_bounds__(64) void qkv_proj_f(
    const float* __restrict__ X, const float* __restrict__ Wq,
    const float* __restrict__ Wk, const float* __restrict__ Wv,
    unsigned short* __restrict__ Qb, unsigned short* __restrict__ Kb,
    unsigned short* __restrict__ VT) {
  const int m0 = blockIdx.x * 64;
  const int n0g = blockIdx.y * 64;
  const int sel = n0g >> 10;
  const int n0 = n0g & 1023;
  const float* W = (sel == 0) ? Wq : (sel == 1) ? Wk : Wv;
  const int lane = threadIdx.x;
  const int c = lane & 15, quad = lane >> 4;

  f32x4 zero = {0.f, 0.f, 0.f, 0.f};
  f32x4 acc[4][4];
#pragma unroll
  for (int i = 0; i < 4; ++i)
#pragma unroll
    for (int j = 0; j < 4; ++j) acc[i][j] = zero;

  const float* ab = X + (size_t)(m0 + c) * DIMN + quad * 8;
  const float* bb = W + (size_t)(n0 + c) * DIMN + quad * 8;

  for (int k0 = 0; k0 < DIMN; k0 += 32) {
    s16x8 a[4], b[4];
#pragma unroll
    for (int i = 0; i < 4; ++i) {
      const float* pp = ab + i * 16 * DIMN + k0;
      a[i] = cvt8(*(const float4*)pp, *(const float4*)(pp + 4));
    }
#pragma unroll
    for (int j = 0; j < 4; ++j) {
      const float* pp = bb + j * 16 * DIMN + k0;
      b[j] = cvt8(*(const float4*)pp, *(const float4*)(pp + 4));
    }
    if (sel != 2) {
#pragma unroll
      for (int i = 0; i < 4; ++i)
#pragma unroll
        for (int j = 0; j < 4; ++j)
          acc[i][j] = __builtin_amdgcn_mfma_f32_16x16x32_bf16(a[i], b[j], acc[i][j], 0, 0, 0);
    } else {
#pragma unroll
      for (int i = 0; i < 4; ++i)
#pragma unroll
        for (int j = 0; j < 4; ++j)
          acc[i][j] = __builtin_amdgcn_mfma_f32_16x16x32_bf16(b[j], a[i], acc[i][j], 0, 0, 0);
    }
  }

  if (sel != 2) {
    unsigned short* Out = (sel == 0) ? Qb : Kb;
    const float scale = (sel == 0) ? QSCALE : 1.0f;
#pragma unroll
    for (int i = 0; i < 4; ++i)
#pragma unroll
      for (int j = 0; j < 4; ++j)
#pragma unroll
        for (int r = 0; r < 4; ++r) {
          int row = m0 + i * 16 + quad * 4 + r;
          int nl = n0 + j * 16 + c;
          int bi = row >> 11, li = row & 2047;
          int h = nl >> 6, d = nl & 63;
          Out[(((size_t)bi * NH + h) * LL + li) * HD + d] = f2bf(acc[i][j][r] * scale);
        }
  } else {
#pragma unroll
    for (int i = 0; i < 4; ++i) {
#pragma unroll
      for (int j = 0; j < 4; ++j)
#pragma unroll
        for (int r = 0; r < 4; ++r) {
          int n = n0 + j * 16 + quad * 4 + r;
          int s128 = (m0 & 64) + i * 16 + c;
          int m = (m0 & ~127) + vpos(s128);
          int h = n >> 6, d = n & 63;
          int bi = m0 >> 11;
          VT[(((size_t)bi * NH + h) * HD + d) * LL + (m & 2047)] = f2bf(acc[i][j][r]);
        }
    }
  }
}

__global__ __launch_bounds__(64) void o_proj_f(
    const unsigned short* __restrict__ A, const float* __restrict__ Wo,
    float* __restrict__ Out) {
  const int m0 = blockIdx.x * 64, n0 = blockIdx.y * 64;
  const int lane = threadIdx.x;
  const int c = lane & 15, quad = lane >> 4;

  f32x4 zero = {0.f, 0.f, 0.f, 0.f};
  f32x4 acc[4][4];
#pragma unroll
  for (int i = 0; i < 4; ++i)
#pragma unroll
    for (int j = 0; j < 4; ++j) acc[i][j] = zero;

  const unsigned short* ab = A + (size_t)(m0 + c) * DIMN + quad * 8;
  const float* bb = Wo + (size_t)(n0 + c) * DIMN + quad * 8;

  for (int k0 = 0; k0 < DIMN; k0 += 32) {
    s16x8 a[4], b[4];
#pragma unroll
    for (int i = 0; i < 4; ++i) a[i] = *(const s16x8*)(ab + i * 16 * DIMN + k0);
#pragma unroll
    for (int j = 0; j < 4; ++j) {
      const float* pp = bb + j * 16 * DIMN + k0;
      b[j] = cvt8(*(const float4*)pp, *(const float4*)(pp + 4));
    }
#pragma unroll
    for (int i = 0; i < 4; ++i)
#pragma unroll
      for (int j = 0; j < 4; ++j)
        acc[i][j] = __builtin_amdgcn_mfma_f32_16x16x32_bf16(a[i], b[j], acc[i][j], 0, 0, 0);
  }

#pragma unroll
  for (int i = 0; i < 4; ++i)
#pragma unroll
    for (int j = 0; j < 4; ++j)
#pragma unroll
      for (int r = 0; r < 4; ++r)
        Out[(size_t)(m0 + i * 16 + quad * 4 + r) * DIMN + n0 + j * 16 + c] = acc[i][j][r];
}

extern "C" void kernel_launch(void* const* d_in, const int* in_sizes, int n_in,
                              void* d_out, int out_size, void* d_ws, size_t ws_size,
                              hipStream_t stream) {
  const float* X = (const float*)d_in[0];
  const float* Wq = (const float*)d_in[1];
  const float* Wk = (const float*)d_in[2];
  const float* Wv = (const float*)d_in[3];
  const float* Wo = (const float*)d_in[4];
  float* Out = (float*)d_out;

  const size_t M1 = (size_t)1 << 20;
  unsigned short* ws16 = (unsigned short*)d_ws;

  if (ws_size >= (size_t)48 * 1024 * 1024) {
    unsigned short* Xb = ws16;            // 4M elems
    unsigned short* Wb = ws16 + 4 * M1;   // 4 x 1M (Wq,Wk,Wv,Wo contiguous)
    unsigned short* Qb = ws16 + 8 * M1;
    unsigned short* Kb = ws16 + 12 * M1;
    unsigned short* VT = ws16 + 16 * M1;
    unsigned short* AO = ws16 + 20 * M1;
    cvt_all<<<4096, 256, 0, stream>>>(X, Wq, Wk, Wv, Wo, ws16);
    gemm_qkv<<<dim3(32, 24), 256, 0, stream>>>(Xb, Wb, Qb, Kb, VT);
    attn6<<<dim3(LL / 128, BB * NH), 512, 0, stream>>>(Qb, Kb, VT, AO);
    gemm_o<<<dim3(32, 16), 256, 0, stream>>>(AO, Wb + 3 * M1, Out);
  } else {
    unsigned short* Qb = ws16;
    unsigned short* Kb = ws16 + 4 * M1;
    unsigned short* VT = ws16 + 8 * M1;
    unsigned short* AO = ws16 + 12 * M1;
    qkv_proj_f<<<dim3(64, 48), 64, 0, stream>>>(X, Wq, Wk, Wv, Qb, Kb, VT);
    attn6<<<dim3(LL / 128, BB * NH), 512, 0, stream>>>(Qb, Kb, VT, AO);
    o_proj_f<<<dim3(64, 16), 64, 0, stream>>>(AO, Wo, Out);
  }
}